// Round 3
// baseline (3127.537 us; speedup 1.0000x reference)
//
#include <hip/hip_runtime.h>
#include <cstdint>
#include <cmath>
#include <cstddef>

// ---------------- problem constants ----------------
constexpr int NN   = 1024;     // nodes
constexpr int NE   = 16384;    // edges
constexpr int HSZ  = 128;      // hidden size
constexpr int NSH  = 25;       // spherical harmonics (l<=4)
constexpr int NRBF = 32;
constexpr int NLAY = 5;
constexpr int XSZ  = HSZ * NSH;   // 3200
constexpr int HII_SZ = NN * 196;  // 200704

// ---------------- ws layout (float offsets) ----------------
constexpr size_t OFF_CONSTS = 0;  // CG 15625 | EXP 4900 | logbinom 32  (20557, pad 20560)
constexpr size_t OFF_X    = 20560;
constexpr size_t OFF_AGG  = OFF_X    + (size_t)NN * XSZ;
constexpr size_t OFF_ATT  = OFF_AGG  + (size_t)NN * XSZ;
constexpr size_t OFF_X0   = OFF_ATT  + (size_t)NN * XSZ;
constexpr size_t OFF_NSC  = OFF_X0   + (size_t)NN * HSZ;
constexpr size_t OFF_Q    = OFF_NSC  + (size_t)NN * HSZ;
constexpr size_t OFF_K    = OFF_Q    + (size_t)NN * HSZ;
constexpr size_t OFF_RBF  = OFF_K    + (size_t)NN * HSZ;
constexpr size_t OFF_SH   = OFF_RBF  + (size_t)NE * NRBF;
constexpr size_t OFF_TK   = OFF_SH   + (size_t)NE * NSH;
constexpr size_t OFF_WRAD = OFF_TK   + (size_t)NE * NSH * NSH;
constexpr size_t OFF_INT  = OFF_WRAD + (size_t)NE * HSZ;   // ints start here
// int region: counts[1024] | starts[1025] | cursor[1024] | perm[16384]
constexpr size_t NEED_BYTES = OFF_INT * 4 + (size_t)(1024 + 1025 + 1024 + 16384) * 4;

// =====================================================================
// Host-side reproduction of np.random.default_rng(7):
// SeedSequence(7) -> PCG64 (XSL-RR 128/64) -> ziggurat standard normal.
// Generates CG (25^3) then EXP (25*14*14) in one stream, *0.1, cast f32.
// FIX (round 2): SeedSequence mix() uses SUBTRACTION (x*L - y*R), not xor —
// matches numpy _seed_seq MIX_MULT_L/R semantics.
// =====================================================================
namespace qhc {

struct Pcg64 {
  unsigned __int128 state, inc;
  static unsigned __int128 mult() {
    return (((unsigned __int128)2549297995355413924ULL) << 64) | 4865540595714422341ULL;
  }
  void step() { state = state * mult() + inc; }
  uint64_t next64() {
    step();
    uint64_t hi = (uint64_t)(state >> 64), lo = (uint64_t)state;
    uint64_t x = hi ^ lo;
    unsigned rot = (unsigned)(state >> 122);
    return (x >> rot) | (x << ((64u - rot) & 63u));
  }
  double nextd() { return (double)(next64() >> 11) * (1.0 / 9007199254740992.0); }
};

struct HostConsts {
  float buf[20560];
  HostConsts() {
    // ---- SeedSequence(7) ----
    const uint32_t INIT_A = 0x43b0d7e5u, MULT_A = 0x931e8875u;
    const uint32_t INIT_B = 0x8b51f9ddu, MULT_B = 0x58f38dedu;
    uint32_t pool[4];
    uint32_t hc = INIT_A;
    auto hashf = [&](uint32_t v) -> uint32_t {
      v ^= hc; hc *= MULT_A; v *= hc; v ^= v >> 16; return v;
    };
    auto mixf = [](uint32_t x, uint32_t y) -> uint32_t {
      uint32_t r = x * 0xca01f9ddu - y * 0x4973f715u;  // SUBTRACT (numpy)
      r ^= r >> 16;
      return r;
    };
    pool[0] = hashf(7u);
    for (int i = 1; i < 4; i++) pool[i] = hashf(0u);
    for (int s = 0; s < 4; s++)
      for (int d = 0; d < 4; d++)
        if (s != d) pool[d] = mixf(pool[d], hashf(pool[s]));
    uint32_t st32[8];
    uint32_t hb = INIT_B;
    for (int i = 0; i < 8; i++) {
      uint32_t v = pool[i % 4];
      v ^= hb; hb *= MULT_B; v *= hb; v ^= v >> 16;
      st32[i] = v;
    }
    uint64_t w0 = st32[0] | ((uint64_t)st32[1] << 32);
    uint64_t w1 = st32[2] | ((uint64_t)st32[3] << 32);
    uint64_t w2 = st32[4] | ((uint64_t)st32[5] << 32);
    uint64_t w3 = st32[6] | ((uint64_t)st32[7] << 32);
    unsigned __int128 seed = (((unsigned __int128)w0) << 64) | w1;
    unsigned __int128 incs = (((unsigned __int128)w2) << 64) | w3;
    Pcg64 g;
    g.state = 0; g.inc = (incs << 1) | 1;
    g.step(); g.state += seed; g.step();
    // ---- ziggurat tables ----
    double wi[256], fi[256]; uint64_t ki[256];
    {
      const double m1 = 4503599627370496.0;  // 2^52
      double dn = 3.6541528853610087963519472518, tn = dn, vn = 0.00492867323399941;
      double q = vn / std::exp(-0.5 * dn * dn);
      ki[0] = (uint64_t)((dn / q) * m1); ki[1] = 0;
      wi[0] = q / m1; wi[255] = dn / m1;
      fi[0] = 1.0; fi[255] = std::exp(-0.5 * dn * dn);
      for (int i = 254; i >= 1; i--) {
        dn = std::sqrt(-2.0 * std::log(vn / dn + std::exp(-0.5 * dn * dn)));
        ki[i + 1] = (uint64_t)((dn / tn) * m1);
        tn = dn;
        fi[i] = std::exp(-0.5 * dn * dn);
        wi[i] = dn / m1;
      }
    }
    const double ZR = 3.6541528853610087963519472518;
    const double ZIR = 0.27366123732975827203338247596;
    auto stdnorm = [&]() -> double {
      for (;;) {
        uint64_t r = g.next64();
        int idx = (int)(r & 0xff);
        r >>= 8;
        int sign = (int)(r & 1);
        uint64_t rabs = (r >> 1) & 0x000fffffffffffffULL;
        double xv = (double)rabs * wi[idx];
        if (sign) xv = -xv;
        if (rabs < ki[idx]) return xv;
        if (idx == 0) {
          for (;;) {
            double xx = -ZIR * std::log1p(-g.nextd());
            double yy = -std::log1p(-g.nextd());
            if (yy + yy > xx * xx)
              return ((rabs >> 8) & 1) ? -(ZR + xx) : (ZR + xx);
          }
        } else {
          if (((fi[idx - 1] - fi[idx]) * g.nextd() + fi[idx]) < std::exp(-0.5 * xv * xv))
            return xv;
        }
      }
    };
    for (int i = 0; i < 15625 + 4900; i++) buf[i] = (float)(0.1 * stdnorm());
    // ---- logbinom for RBF ----
    double logf[32]; logf[0] = 0.0;
    for (int i = 1; i < 32; i++) logf[i] = logf[i - 1] + std::log((double)i);
    for (int k = 0; k < 32; k++) buf[15625 + 4900 + k] = (float)(logf[31] - logf[k] - logf[31 - k]);
    buf[20557] = buf[20558] = buf[20559] = 0.f;
  }
};
static HostConsts g_hc;
}  // namespace qhc

// =====================================================================
// device helpers
// =====================================================================
__device__ __forceinline__ int lbof(int m) {
  return (m == 0) ? 0 : ((m < 4) ? 1 : ((m < 9) ? 2 : ((m < 16) ? 3 : 4)));
}
__device__ __forceinline__ float siluf(float a) { return a / (1.f + expf(-a)); }

// ---------------- edge geometry: sh + rbf ----------------
__global__ __launch_bounds__(256) void qh_geom(
    const float* __restrict__ pos, const int* __restrict__ ei,
    const float* __restrict__ lbn, float* __restrict__ rbf, float* __restrict__ sh) {
  int e = blockIdx.x * 256 + threadIdx.x;
  if (e >= NE) return;
  int s = ei[e], d = ei[NE + e];
  float vx = pos[s * 3 + 0] - pos[d * 3 + 0];
  float vy = pos[s * 3 + 1] - pos[d * 3 + 1];
  float vz = pos[s * 3 + 2] - pos[d * 3 + 2];
  float r = sqrtf(vx * vx + vy * vy + vz * vz + 1e-12f);
  float inv = 1.0f / r;
  float x = vx * inv, y = vy * inv, z = vz * inv;
  float x2 = x * x, y2 = y * y, z2 = z * z;
  float* sp = sh + (size_t)e * NSH;
  sp[0] = 0.282095f;
  sp[1] = 0.488603f * y;
  sp[2] = 0.488603f * z;
  sp[3] = 0.488603f * x;
  sp[4] = 1.092548f * x * y;
  sp[5] = 1.092548f * y * z;
  sp[6] = 0.315392f * (3.f * z2 - 1.f);
  sp[7] = 1.092548f * x * z;
  sp[8] = 0.546274f * (x2 - y2);
  sp[9] = 0.590044f * y * (3.f * x2 - y2);
  sp[10] = 2.890611f * x * y * z;
  sp[11] = 0.457046f * y * (5.f * z2 - 1.f);
  sp[12] = 0.373176f * z * (5.f * z2 - 3.f);
  sp[13] = 0.457046f * x * (5.f * z2 - 1.f);
  sp[14] = 1.445306f * z * (x2 - y2);
  sp[15] = 0.590044f * x * (x2 - 3.f * y2);
  sp[16] = 2.503343f * x * y * (x2 - y2);
  sp[17] = 1.770131f * y * z * (3.f * x2 - y2);
  sp[18] = 0.946175f * x * y * (7.f * z2 - 1.f);
  sp[19] = 0.669047f * y * z * (7.f * z2 - 3.f);
  sp[20] = 0.105786f * (35.f * z2 * z2 - 30.f * z2 + 3.f);
  sp[21] = 0.669047f * x * z * (7.f * z2 - 3.f);
  sp[22] = 0.473087f * (x2 - y2) * (7.f * z2 - 1.f);
  sp[23] = 1.770131f * x * z * (x2 - 3.f * y2);
  sp[24] = 0.625836f * (x2 * x2 - 6.f * x2 * y2 + y2 * y2);
  float xr = expf(-0.5f * r);
  float l1 = log1pf(-xr + 1e-7f);
  float fc = 0.5f * (cosf(3.14159265358979323846f * fminf(r * (1.0f / 12.0f), 1.0f)) + 1.0f);
  float* rp = rbf + (size_t)e * NRBF;
  for (int k = 0; k < NRBF; k++) {
    float b = expf(lbn[k] + (float)k * (-0.5f * r) + (float)(NRBF - 1 - k) * l1);
    rp[k] = b * fc;
  }
}

// ---------------- Tk[e,i,k] = sum_j sh[e,j]*CG[i,j,k]  (layer-invariant) ----------------
__global__ __launch_bounds__(256) void qh_tk(
    const float* __restrict__ sh, const float* __restrict__ CG, float* __restrict__ Tk) {
  __shared__ float shl[32 * NSH];
  int e0 = blockIdx.x * 32;
  int t = threadIdx.x;
  for (int i = t; i < 32 * NSH; i += 256) shl[i] = sh[(size_t)e0 * NSH + i];
  __syncthreads();
  for (int ik = t; ik < NSH * NSH; ik += 256) {
    int i = ik / NSH, k = ik % NSH;
    float cg[NSH];
#pragma unroll
    for (int j = 0; j < NSH; j++) cg[j] = CG[i * 625 + j * NSH + k];
    for (int ee = 0; ee < 32; ee++) {
      float acc = 0.f;
#pragma unroll
      for (int j = 0; j < NSH; j++) acc += shl[ee * NSH + j] * cg[j];
      Tk[(size_t)(e0 + ee) * 625 + ik] = acc;
    }
  }
}

// ---------------- node scalar MLP + init x ----------------
__global__ __launch_bounds__(128) void qh_nsc(
    const int* __restrict__ z, const int* __restrict__ tptr, const int* __restrict__ sptr,
    const float* __restrict__ embed, const float* __restrict__ tT, const float* __restrict__ tH,
    const float* __restrict__ W1, const float* __restrict__ b1,
    const float* __restrict__ W2, const float* __restrict__ b2,
    float* __restrict__ nsc, float* __restrict__ x, float* __restrict__ x0) {
  __shared__ float cat[384];
  __shared__ float h[128];
  int nd = blockIdx.x, d = threadIdx.x;
  int zz = z[nd], tt = tptr[0], st = sptr[0];
  cat[d] = embed[zz * HSZ + d];
  cat[128 + d] = tT[tt * HSZ + d];
  cat[256 + d] = tH[st * HSZ + d];
  __syncthreads();
  float a = b1[d];
  for (int c = 0; c < 384; c++) a += cat[c] * W1[c * HSZ + d];
  h[d] = fmaxf(a, 0.f);
  __syncthreads();
  a = b2[d];
  for (int c = 0; c < 128; c++) a += h[c] * W2[c * HSZ + d];
  nsc[nd * HSZ + d] = a;
  x0[nd * HSZ + d] = a;
  float* xr = x + (size_t)nd * XSZ + d * NSH;
  xr[0] = a;
  for (int k = 1; k < NSH; k++) xr[k] = 0.f;
}

// ---------------- dst-bucket sort ----------------
__global__ __launch_bounds__(256) void qh_zero(int* counts) {
  int i = blockIdx.x * 256 + threadIdx.x;
  if (i < NN) counts[i] = 0;
}
__global__ __launch_bounds__(256) void qh_count(const int* __restrict__ ei, int* counts) {
  int e = blockIdx.x * 256 + threadIdx.x;
  if (e < NE) atomicAdd(&counts[ei[NE + e]], 1);
}
__global__ __launch_bounds__(1024) void qh_scan(const int* __restrict__ counts,
                                                int* starts, int* cursor) {
  __shared__ int tmp[NN];
  int t = threadIdx.x;
  tmp[t] = counts[t];
  __syncthreads();
  for (int ofs = 1; ofs < NN; ofs <<= 1) {
    int v = (t >= ofs) ? tmp[t - ofs] : 0;
    __syncthreads();
    tmp[t] += v;
    __syncthreads();
  }
  starts[t + 1] = tmp[t];
  if (t == 0) starts[0] = 0;
  cursor[t] = (t == 0) ? 0 : tmp[t - 1];
}
__global__ __launch_bounds__(256) void qh_scatter(const int* __restrict__ ei,
                                                  int* cursor, int* perm) {
  int e = blockIdx.x * 256 + threadIdx.x;
  if (e < NE) {
    int d = ei[NE + e];
    int pos = atomicAdd(&cursor[d], 1);
    perm[pos] = e;
  }
}

// ---------------- radial MLP: 16 edges per block, weights in LDS ----------------
__global__ __launch_bounds__(128) void qh_rad(
    const float* __restrict__ rbf,
    const float* __restrict__ W1, const float* __restrict__ b1,
    const float* __restrict__ W2, const float* __restrict__ b2,
    const float* __restrict__ W3, const float* __restrict__ b3,
    float* __restrict__ wrad) {
  __shared__ float w1l[32 * 64], w2l[64 * 64], w3l[64 * 128];
  __shared__ float rl[32], h1[64], h2[64];
  int t = threadIdx.x;
  for (int i = t; i < 32 * 64; i += 128) w1l[i] = W1[i];
  for (int i = t; i < 64 * 64; i += 128) w2l[i] = W2[i];
  for (int i = t; i < 64 * 128; i += 128) w3l[i] = W3[i];
  float b3t = b3[t];
  float b1t = (t < 64) ? b1[t] : 0.f;
  float b2t = (t < 64) ? b2[t] : 0.f;
  __syncthreads();
  int e0 = blockIdx.x * 16;
  for (int ee = 0; ee < 16; ee++) {
    int e = e0 + ee;
    if (t < 32) rl[t] = rbf[(size_t)e * NRBF + t];
    __syncthreads();
    if (t < 64) {
      float a = b1t;
      for (int c = 0; c < 32; c++) a += rl[c] * w1l[c * 64 + t];
      h1[t] = siluf(a);
    }
    __syncthreads();
    if (t < 64) {
      float a = b2t;
      for (int c = 0; c < 64; c++) a += h1[c] * w2l[c * 64 + t];
      h2[t] = siluf(a);
    }
    __syncthreads();
    float a = b3t;
    for (int c = 0; c < 64; c++) a += h2[c] * w3l[c * 128 + t];
    wrad[(size_t)e * HSZ + t] = a;
    __syncthreads();
  }
}

// ---------------- q/k projections ----------------
__global__ __launch_bounds__(256) void qh_qk(
    const float* __restrict__ x0, const float* __restrict__ Wq, const float* __restrict__ Wk,
    float* __restrict__ q, float* __restrict__ kk) {
  __shared__ float xl[128];
  int nd = blockIdx.x, t = threadIdx.x;
  if (t < 128) xl[t] = x0[nd * HSZ + t];
  __syncthreads();
  int d = t & 127;
  const float* W = (t < 128) ? Wq : Wk;
  float a = 0.f;
  for (int c = 0; c < 128; c++) a += xl[c] * W[c * HSZ + d];
  if (t < 128) q[nd * HSZ + d] = a;
  else kk[nd * HSZ + d] = a;
}

// ---------------- fused message + segment_sum (per dst node) ----------------
__global__ __launch_bounds__(256) void qh_msg(
    const float* __restrict__ x, const float* __restrict__ Tk, const float* __restrict__ wrad,
    const int* __restrict__ starts, const int* __restrict__ perm, const int* __restrict__ ei,
    float* __restrict__ agg) {
  __shared__ float xs[XSZ];
  __shared__ float tkl[625];
  __shared__ float wl[128];
  int nd = blockIdx.x, t = threadIdx.x;
  int c = t & 127, hf = t >> 7;
  int k0 = hf ? 13 : 0, nk = hf ? 12 : 13;
  float acc[13];
#pragma unroll
  for (int u = 0; u < 13; u++) acc[u] = 0.f;
  int jb = starts[nd], je = starts[nd + 1];
  for (int j = jb; j < je; j++) {
    int e = perm[j];
    int s = ei[e];
    for (int i = t; i < XSZ; i += 256) xs[i] = x[(size_t)s * XSZ + i];
    for (int i = t; i < 625; i += 256) tkl[i] = Tk[(size_t)e * 625 + i];
    if (t < 128) wl[t] = wrad[(size_t)e * HSZ + t];
    __syncthreads();
    float wc = wl[c];
    for (int i = 0; i < NSH; i++) {
      float xv = xs[c * NSH + i] * wc;
      const float* tr = &tkl[i * NSH + k0];
#pragma unroll
      for (int u = 0; u < 13; u++) {
        if (u < nk) acc[u] += xv * tr[u];
      }
    }
    __syncthreads();
  }
  float* ag = agg + (size_t)nd * XSZ + c * NSH + k0;
#pragma unroll
  for (int u = 0; u < 13; u++)
    if (u < nk) ag[u] = acc[u];
}

// ---------------- attention (per dst node, online softmax) ----------------
__global__ __launch_bounds__(256) void qh_att(
    const float* __restrict__ x, const float* __restrict__ q, const float* __restrict__ kk,
    const int* __restrict__ starts, const int* __restrict__ perm, const int* __restrict__ ei,
    float* __restrict__ att) {
  __shared__ float ql[128];
  __shared__ float xs[XSZ];
  __shared__ float alph[4];
  __shared__ float mden[8];
  int nd = blockIdx.x, t = threadIdx.x;
  if (t < 128) ql[t] = q[nd * HSZ + t];
  int jb = starts[nd], je = starts[nd + 1];
  __syncthreads();
  // pass 1: online max/denominator per head
  if (t < 4) {
    float m = -1e30f, den = 0.f;
    for (int j = jb; j < je; j++) {
      int e = perm[j], s = ei[e];
      float lg = 0.f;
#pragma unroll
      for (int dd = 0; dd < 32; dd++) lg += ql[t * 32 + dd] * kk[s * HSZ + t * 32 + dd];
      lg *= 0.17677669529663687f;
      float mn = fmaxf(m, lg);
      den = den * expf(m - mn) + expf(lg - mn);
      m = mn;
    }
    mden[t] = m;
    mden[4 + t] = den;
  }
  __syncthreads();
  int c = t & 127, hf = t >> 7;
  int k0 = hf ? 13 : 0, nk = hf ? 12 : 13;
  float acc[13];
#pragma unroll
  for (int u = 0; u < 13; u++) acc[u] = 0.f;
  for (int j = jb; j < je; j++) {
    int e = perm[j], s = ei[e];
    if (t < 4) {
      float lg = 0.f;
#pragma unroll
      for (int dd = 0; dd < 32; dd++) lg += ql[t * 32 + dd] * kk[s * HSZ + t * 32 + dd];
      lg *= 0.17677669529663687f;
      alph[t] = expf(lg - mden[t]) / (mden[4 + t] + 1e-9f);
    }
    for (int i = t; i < XSZ; i += 256) xs[i] = x[(size_t)s * XSZ + i];
    __syncthreads();
    float al = alph[c >> 5];
    const float* xr = &xs[c * NSH + k0];
#pragma unroll
    for (int u = 0; u < 13; u++)
      if (u < nk) acc[u] += al * xr[u];
    __syncthreads();
  }
  float* at = att + (size_t)nd * XSZ + c * NSH + k0;
#pragma unroll
  for (int u = 0; u < 13; u++)
    if (u < nk) at[u] = acc[u];
}

// ---------------- y = mix(agg); x = gate(x + y + att) ----------------
__global__ __launch_bounds__(256) void qh_mix(
    const float* __restrict__ agg, const float* __restrict__ att,
    const float* __restrict__ mixW, float* __restrict__ x, float* __restrict__ x0) {
  __shared__ float Wl[8192];
  __shared__ float aggl[XSZ];
  __shared__ float v0l[128];
  int nd = blockIdx.x, t = threadIdx.x;
  for (int i = t; i < XSZ; i += 256) aggl[i] = agg[(size_t)nd * XSZ + i];
  int d = t & 127, hf = t >> 7;
  int k0 = hf ? 13 : 0, nk = hf ? 12 : 13;
  float v[13];
#pragma unroll
  for (int u = 0; u < 13; u++) v[u] = 0.f;
  for (int lb = 0; lb < 5; lb++) {
    int o = lb * lb, sl = 2 * lb + 1;
    for (int ch = 0; ch < 2; ch++) {
      __syncthreads();
      for (int i = t; i < 8192; i += 256) Wl[i] = mixW[lb * 16384 + ch * 8192 + i];
      __syncthreads();
#pragma unroll
      for (int u = 0; u < 13; u++) {
        int m = k0 + u;
        if (u < nk && m >= o && m < o + sl) {
          float a = 0.f;
          for (int cc = 0; cc < 64; cc++) a += aggl[(ch * 64 + cc) * NSH + m] * Wl[cc * 128 + d];
          v[u] += a;
        }
      }
    }
  }
  size_t base = (size_t)nd * XSZ + d * NSH + k0;
#pragma unroll
  for (int u = 0; u < 13; u++)
    if (u < nk) v[u] += x[base + u] + att[base + u];
  if (hf == 0) v0l[d] = v[0];
  __syncthreads();
  float g = 1.f / (1.f + expf(-v0l[d]));
#pragma unroll
  for (int u = 0; u < 13; u++)
    if (u < nk) x[base + u] = v[u] * g;
  if (hf == 0) x0[nd * HSZ + d] = v[0] * g;
}

// ---------------- H_ii (per node) ----------------
__global__ __launch_bounds__(256) void qh_fii(
    const float* __restrict__ x, const float* __restrict__ nsc,
    const float* __restrict__ Wii, const float* __restrict__ pii,
    const float* __restrict__ EXPc, float* __restrict__ out) {
  __shared__ float xl[XSZ], nl[128], wl[32], wv[640], gl[25];
  int nd = blockIdx.x, t = threadIdx.x;
  for (int i = t; i < XSZ; i += 256) xl[i] = x[(size_t)nd * XSZ + i];
  if (t < 128) nl[t] = nsc[nd * HSZ + t];
  __syncthreads();
  if (t < 32) {
    float a = 0.f;
    for (int c = 0; c < 128; c++) a += nl[c] * pii[c * 32 + t];
    wl[t] = a;
  }
  __syncthreads();
  for (int i = t; i < 640; i += 256) {
    int lb = i >> 7, c = i & 127;
    float a = 0.f;
#pragma unroll
    for (int dd = 0; dd < 32; dd++) a += Wii[lb * 4096 + c * 32 + dd] * wl[dd];
    wv[i] = a;
  }
  __syncthreads();
  if (t < 25) {
    int lb = lbof(t);
    float a = 0.f;
    for (int c = 0; c < 128; c++) a += xl[c * NSH + t] * wv[lb * 128 + c];
    gl[t] = a;
  }
  __syncthreads();
  if (t < 196) {
    float a = 0.f;
#pragma unroll
    for (int m = 0; m < 25; m++) a += gl[m] * EXPc[m * 196 + t];
    out[(size_t)nd * 196 + t] = a;
  }
}

// ---------------- H_ij (per edge) ----------------
__global__ __launch_bounds__(256) void qh_fij(
    const float* __restrict__ x, const float* __restrict__ nsc, const int* __restrict__ ei,
    const float* __restrict__ Wij, const float* __restrict__ pij,
    const float* __restrict__ EXPc, float* __restrict__ out) {
  __shared__ float xl[XSZ], nls[128], nld[128], wl[32], wv[640], gl[25];
  int e = blockIdx.x, t = threadIdx.x;
  int s = ei[e], nd2 = ei[NE + e];
  for (int i = t; i < XSZ; i += 256)
    xl[i] = x[(size_t)s * XSZ + i] + x[(size_t)nd2 * XSZ + i];
  if (t < 128) nls[t] = nsc[s * HSZ + t];
  else nld[t - 128] = nsc[nd2 * HSZ + (t - 128)];
  __syncthreads();
  if (t < 32) {
    float a = 0.f;
    for (int c = 0; c < 128; c++) a += nls[c] * pij[c * 32 + t];
    for (int c = 0; c < 128; c++) a += nld[c] * pij[(128 + c) * 32 + t];
    wl[t] = a;
  }
  __syncthreads();
  for (int i = t; i < 640; i += 256) {
    int lb = i >> 7, c = i & 127;
    float a = 0.f;
#pragma unroll
    for (int dd = 0; dd < 32; dd++) a += Wij[lb * 4096 + c * 32 + dd] * wl[dd];
    wv[i] = a;
  }
  __syncthreads();
  if (t < 25) {
    int lb = lbof(t);
    float a = 0.f;
    for (int c = 0; c < 128; c++) a += xl[c * NSH + t] * wv[lb * 128 + c];
    gl[t] = a;
  }
  __syncthreads();
  if (t < 196) {
    float a = 0.f;
#pragma unroll
    for (int m = 0; m < 25; m++) a += gl[m] * EXPc[m * 196 + t];
    out[HII_SZ + (size_t)e * 196 + t] = a;
  }
}

// =====================================================================
extern "C" void kernel_launch(void* const* d_in, const int* in_sizes, int n_in,
                              void* d_out, int out_size, void* d_ws, size_t ws_size,
                              hipStream_t stream) {
  (void)in_sizes; (void)n_in; (void)out_size;
  if (ws_size < NEED_BYTES) return;  // workspace too small — cannot run

  const int*   z    = (const int*)d_in[0];
  const float* pos  = (const float*)d_in[1];
  const int*   ei   = (const int*)d_in[2];
  // d_in[3] = batch (unused)
  const int*   tptr = (const int*)d_in[4];
  const int*   sptr = (const int*)d_in[5];
  const float* embed= (const float*)d_in[6];
  const float* tT   = (const float*)d_in[7];
  const float* tH   = (const float*)d_in[8];
  const float* sW1  = (const float*)d_in[9];
  const float* sb1  = (const float*)d_in[10];
  const float* sW2  = (const float*)d_in[11];
  const float* sb2  = (const float*)d_in[12];
  const float* rW1  = (const float*)d_in[13];
  const float* rb1  = (const float*)d_in[14];
  const float* rW2  = (const float*)d_in[15];
  const float* rb2  = (const float*)d_in[16];
  const float* rW3  = (const float*)d_in[17];
  const float* rb3  = (const float*)d_in[18];
  const float* mixW = (const float*)d_in[19];
  const float* Wq   = (const float*)d_in[20];
  const float* Wk   = (const float*)d_in[21];
  const float* Wii  = (const float*)d_in[22];
  const float* Wij  = (const float*)d_in[23];
  const float* pii  = (const float*)d_in[24];
  const float* pij  = (const float*)d_in[25];

  float* ws = (float*)d_ws;
  float* CGd   = ws + OFF_CONSTS;
  float* EXPd  = CGd + 15625;
  float* LBNd  = CGd + 15625 + 4900;
  float* x     = ws + OFF_X;
  float* agg   = ws + OFF_AGG;
  float* att   = ws + OFF_ATT;
  float* x0    = ws + OFF_X0;
  float* nsc   = ws + OFF_NSC;
  float* qarr  = ws + OFF_Q;
  float* karr  = ws + OFF_K;
  float* rbf   = ws + OFF_RBF;
  float* sh    = ws + OFF_SH;
  float* Tk    = ws + OFF_TK;
  float* wrad  = ws + OFF_WRAD;
  int* ibase   = (int*)(ws + OFF_INT);
  int* counts  = ibase;
  int* starts  = ibase + 1024;
  int* cursor  = ibase + 1024 + 1025;
  int* perm    = ibase + 1024 + 1025 + 1024;
  float* outp  = (float*)d_out;

  // constants (CG, EXP, logbinom) — static host buffer, captured as memcpy node
  hipMemcpyAsync(CGd, qhc::g_hc.buf, 20557 * sizeof(float), hipMemcpyHostToDevice, stream);

  qh_geom<<<NE / 256, 256, 0, stream>>>(pos, ei, LBNd, rbf, sh);
  qh_tk<<<NE / 32, 256, 0, stream>>>(sh, CGd, Tk);
  qh_nsc<<<NN, 128, 0, stream>>>(z, tptr, sptr, embed, tT, tH, sW1, sb1, sW2, sb2, nsc, x, x0);
  qh_zero<<<NN / 256, 256, 0, stream>>>(counts);
  qh_count<<<NE / 256, 256, 0, stream>>>(ei, counts);
  qh_scan<<<1, 1024, 0, stream>>>(counts, starts, cursor);
  qh_scatter<<<NE / 256, 256, 0, stream>>>(ei, cursor, perm);

  for (int l = 0; l < NLAY; l++) {
    qh_rad<<<NE / 16, 128, 0, stream>>>(rbf,
        rW1 + (size_t)l * 32 * 64, rb1 + (size_t)l * 64,
        rW2 + (size_t)l * 64 * 64, rb2 + (size_t)l * 64,
        rW3 + (size_t)l * 64 * 128, rb3 + (size_t)l * 128, wrad);
    qh_qk<<<NN, 256, 0, stream>>>(x0, Wq + (size_t)l * 16384, Wk + (size_t)l * 16384, qarr, karr);
    qh_msg<<<NN, 256, 0, stream>>>(x, Tk, wrad, starts, perm, ei, agg);
    qh_att<<<NN, 256, 0, stream>>>(x, qarr, karr, starts, perm, ei, att);
    qh_mix<<<NN, 256, 0, stream>>>(agg, att, mixW + (size_t)l * 81920, x, x0);
  }

  qh_fii<<<NN, 256, 0, stream>>>(x, nsc, Wii, pii, EXPd, outp);
  qh_fij<<<NE, 256, 0, stream>>>(x, nsc, ei, Wij, pij, EXPd, outp);
}

// Round 4
// 1894.419 us; speedup vs baseline: 1.6509x; 1.6509x over previous
//
#include <hip/hip_runtime.h>
#include <cstdint>
#include <cmath>
#include <cstddef>

// ---------------- problem constants ----------------
constexpr int NN   = 1024;     // nodes
constexpr int NE   = 16384;    // edges
constexpr int HSZ  = 128;      // hidden size
constexpr int NSH  = 25;       // spherical harmonics (l<=4)
constexpr int NRBF = 32;
constexpr int NLAY = 5;
constexpr int XSZ  = HSZ * NSH;   // 3200
constexpr int HII_SZ = NN * 196;  // 200704

// ---------------- ws layout (float offsets) ----------------
constexpr size_t OFF_CONSTS = 0;  // CG 15625 | EXP 4900 | logbinom 32  (20557, pad 20560)
constexpr size_t OFF_X    = 20560;
constexpr size_t OFF_AGG  = OFF_X    + (size_t)NN * XSZ;
constexpr size_t OFF_ATT  = OFF_AGG  + (size_t)NN * XSZ;
constexpr size_t OFF_X0   = OFF_ATT  + (size_t)NN * XSZ;
constexpr size_t OFF_NSC  = OFF_X0   + (size_t)NN * HSZ;
constexpr size_t OFF_Q    = OFF_NSC  + (size_t)NN * HSZ;
constexpr size_t OFF_K    = OFF_Q    + (size_t)NN * HSZ;
constexpr size_t OFF_RBF  = OFF_K    + (size_t)NN * HSZ;
constexpr size_t OFF_SH   = OFF_RBF  + (size_t)NE * NRBF;
constexpr size_t OFF_TK   = OFF_SH   + (size_t)NE * NSH;
constexpr size_t OFF_WRAD = OFF_TK   + (size_t)NE * NSH * NSH;
constexpr size_t OFF_INT  = OFF_WRAD + (size_t)NE * HSZ;   // ints start here
// int region: counts[1024] | starts[1025] | cursor[1024] | perm[16384]
constexpr size_t NEED_BYTES = OFF_INT * 4 + (size_t)(1024 + 1025 + 1024 + 16384) * 4;
// aliased (dead-region) buffers:
//   logits -> OFF_SH          (sh dead after qh_tk)        65536 floats
//   alpha  -> OFF_SH + 65536                                65536 floats
//   fm     -> OFF_AGG         (agg dead after layer loop)  819200 floats
//   awb    -> OFF_AGG + 819200                              65536 floats

// =====================================================================
// Host-side reproduction of np.random.default_rng(7) (verified round 3).
// =====================================================================
namespace qhc {

struct Pcg64 {
  unsigned __int128 state, inc;
  static unsigned __int128 mult() {
    return (((unsigned __int128)2549297995355413924ULL) << 64) | 4865540595714422341ULL;
  }
  void step() { state = state * mult() + inc; }
  uint64_t next64() {
    step();
    uint64_t hi = (uint64_t)(state >> 64), lo = (uint64_t)state;
    uint64_t x = hi ^ lo;
    unsigned rot = (unsigned)(state >> 122);
    return (x >> rot) | (x << ((64u - rot) & 63u));
  }
  double nextd() { return (double)(next64() >> 11) * (1.0 / 9007199254740992.0); }
};

struct HostConsts {
  float buf[20560];
  HostConsts() {
    const uint32_t INIT_A = 0x43b0d7e5u, MULT_A = 0x931e8875u;
    const uint32_t INIT_B = 0x8b51f9ddu, MULT_B = 0x58f38dedu;
    uint32_t pool[4];
    uint32_t hc = INIT_A;
    auto hashf = [&](uint32_t v) -> uint32_t {
      v ^= hc; hc *= MULT_A; v *= hc; v ^= v >> 16; return v;
    };
    auto mixf = [](uint32_t x, uint32_t y) -> uint32_t {
      uint32_t r = x * 0xca01f9ddu - y * 0x4973f715u;  // SUBTRACT (numpy)
      r ^= r >> 16;
      return r;
    };
    pool[0] = hashf(7u);
    for (int i = 1; i < 4; i++) pool[i] = hashf(0u);
    for (int s = 0; s < 4; s++)
      for (int d = 0; d < 4; d++)
        if (s != d) pool[d] = mixf(pool[d], hashf(pool[s]));
    uint32_t st32[8];
    uint32_t hb = INIT_B;
    for (int i = 0; i < 8; i++) {
      uint32_t v = pool[i % 4];
      v ^= hb; hb *= MULT_B; v *= hb; v ^= v >> 16;
      st32[i] = v;
    }
    uint64_t w0 = st32[0] | ((uint64_t)st32[1] << 32);
    uint64_t w1 = st32[2] | ((uint64_t)st32[3] << 32);
    uint64_t w2 = st32[4] | ((uint64_t)st32[5] << 32);
    uint64_t w3 = st32[6] | ((uint64_t)st32[7] << 32);
    unsigned __int128 seed = (((unsigned __int128)w0) << 64) | w1;
    unsigned __int128 incs = (((unsigned __int128)w2) << 64) | w3;
    Pcg64 g;
    g.state = 0; g.inc = (incs << 1) | 1;
    g.step(); g.state += seed; g.step();
    double wi[256], fi[256]; uint64_t ki[256];
    {
      const double m1 = 4503599627370496.0;  // 2^52
      double dn = 3.6541528853610087963519472518, tn = dn, vn = 0.00492867323399941;
      double q = vn / std::exp(-0.5 * dn * dn);
      ki[0] = (uint64_t)((dn / q) * m1); ki[1] = 0;
      wi[0] = q / m1; wi[255] = dn / m1;
      fi[0] = 1.0; fi[255] = std::exp(-0.5 * dn * dn);
      for (int i = 254; i >= 1; i--) {
        dn = std::sqrt(-2.0 * std::log(vn / dn + std::exp(-0.5 * dn * dn)));
        ki[i + 1] = (uint64_t)((dn / tn) * m1);
        tn = dn;
        fi[i] = std::exp(-0.5 * dn * dn);
        wi[i] = dn / m1;
      }
    }
    const double ZR = 3.6541528853610087963519472518;
    const double ZIR = 0.27366123732975827203338247596;
    auto stdnorm = [&]() -> double {
      for (;;) {
        uint64_t r = g.next64();
        int idx = (int)(r & 0xff);
        r >>= 8;
        int sign = (int)(r & 1);
        uint64_t rabs = (r >> 1) & 0x000fffffffffffffULL;
        double xv = (double)rabs * wi[idx];
        if (sign) xv = -xv;
        if (rabs < ki[idx]) return xv;
        if (idx == 0) {
          for (;;) {
            double xx = -ZIR * std::log1p(-g.nextd());
            double yy = -std::log1p(-g.nextd());
            if (yy + yy > xx * xx)
              return ((rabs >> 8) & 1) ? -(ZR + xx) : (ZR + xx);
          }
        } else {
          if (((fi[idx - 1] - fi[idx]) * g.nextd() + fi[idx]) < std::exp(-0.5 * xv * xv))
            return xv;
        }
      }
    };
    for (int i = 0; i < 15625 + 4900; i++) buf[i] = (float)(0.1 * stdnorm());
    double logf[32]; logf[0] = 0.0;
    for (int i = 1; i < 32; i++) logf[i] = logf[i - 1] + std::log((double)i);
    for (int k = 0; k < 32; k++) buf[15625 + 4900 + k] = (float)(logf[31] - logf[k] - logf[31 - k]);
    buf[20557] = buf[20558] = buf[20559] = 0.f;
  }
};
static HostConsts g_hc;
}  // namespace qhc

// =====================================================================
__device__ __forceinline__ float siluf(float a) { return a / (1.f + expf(-a)); }

// ---------------- edge geometry: sh + rbf ----------------
__global__ __launch_bounds__(256) void qh_geom(
    const float* __restrict__ pos, const int* __restrict__ ei,
    const float* __restrict__ lbn, float* __restrict__ rbf, float* __restrict__ sh) {
  int e = blockIdx.x * 256 + threadIdx.x;
  if (e >= NE) return;
  int s = ei[e], d = ei[NE + e];
  float vx = pos[s * 3 + 0] - pos[d * 3 + 0];
  float vy = pos[s * 3 + 1] - pos[d * 3 + 1];
  float vz = pos[s * 3 + 2] - pos[d * 3 + 2];
  float r = sqrtf(vx * vx + vy * vy + vz * vz + 1e-12f);
  float inv = 1.0f / r;
  float x = vx * inv, y = vy * inv, z = vz * inv;
  float x2 = x * x, y2 = y * y, z2 = z * z;
  float* sp = sh + (size_t)e * NSH;
  sp[0] = 0.282095f;
  sp[1] = 0.488603f * y;
  sp[2] = 0.488603f * z;
  sp[3] = 0.488603f * x;
  sp[4] = 1.092548f * x * y;
  sp[5] = 1.092548f * y * z;
  sp[6] = 0.315392f * (3.f * z2 - 1.f);
  sp[7] = 1.092548f * x * z;
  sp[8] = 0.546274f * (x2 - y2);
  sp[9] = 0.590044f * y * (3.f * x2 - y2);
  sp[10] = 2.890611f * x * y * z;
  sp[11] = 0.457046f * y * (5.f * z2 - 1.f);
  sp[12] = 0.373176f * z * (5.f * z2 - 3.f);
  sp[13] = 0.457046f * x * (5.f * z2 - 1.f);
  sp[14] = 1.445306f * z * (x2 - y2);
  sp[15] = 0.590044f * x * (x2 - 3.f * y2);
  sp[16] = 2.503343f * x * y * (x2 - y2);
  sp[17] = 1.770131f * y * z * (3.f * x2 - y2);
  sp[18] = 0.946175f * x * y * (7.f * z2 - 1.f);
  sp[19] = 0.669047f * y * z * (7.f * z2 - 3.f);
  sp[20] = 0.105786f * (35.f * z2 * z2 - 30.f * z2 + 3.f);
  sp[21] = 0.669047f * x * z * (7.f * z2 - 3.f);
  sp[22] = 0.473087f * (x2 - y2) * (7.f * z2 - 1.f);
  sp[23] = 1.770131f * x * z * (x2 - 3.f * y2);
  sp[24] = 0.625836f * (x2 * x2 - 6.f * x2 * y2 + y2 * y2);
  float xr = expf(-0.5f * r);
  float l1 = log1pf(-xr + 1e-7f);
  float fc = 0.5f * (cosf(3.14159265358979323846f * fminf(r * (1.0f / 12.0f), 1.0f)) + 1.0f);
  float* rp = rbf + (size_t)e * NRBF;
  for (int k = 0; k < NRBF; k++) {
    float b = expf(lbn[k] + (float)k * (-0.5f * r) + (float)(NRBF - 1 - k) * l1);
    rp[k] = b * fc;
  }
}

// ---------------- Tk[e,i,k] = sum_j sh[e,j]*CG[i,j,k] ----------------
__global__ __launch_bounds__(256) void qh_tk(
    const float* __restrict__ sh, const float* __restrict__ CG, float* __restrict__ Tk) {
  __shared__ float shl[32 * NSH];
  int e0 = blockIdx.x * 32;
  int t = threadIdx.x;
  for (int i = t; i < 32 * NSH; i += 256) shl[i] = sh[(size_t)e0 * NSH + i];
  __syncthreads();
  for (int ik = t; ik < NSH * NSH; ik += 256) {
    int i = ik / NSH, k = ik % NSH;
    float cg[NSH];
#pragma unroll
    for (int j = 0; j < NSH; j++) cg[j] = CG[i * 625 + j * NSH + k];
    for (int ee = 0; ee < 32; ee++) {
      float acc = 0.f;
#pragma unroll
      for (int j = 0; j < NSH; j++) acc += shl[ee * NSH + j] * cg[j];
      Tk[(size_t)(e0 + ee) * 625 + ik] = acc;
    }
  }
}

// ---------------- node scalar MLP + init x ----------------
__global__ __launch_bounds__(128) void qh_nsc(
    const int* __restrict__ z, const int* __restrict__ tptr, const int* __restrict__ sptr,
    const float* __restrict__ embed, const float* __restrict__ tT, const float* __restrict__ tH,
    const float* __restrict__ W1, const float* __restrict__ b1,
    const float* __restrict__ W2, const float* __restrict__ b2,
    float* __restrict__ nsc, float* __restrict__ x, float* __restrict__ x0) {
  __shared__ float cat[384];
  __shared__ float h[128];
  int nd = blockIdx.x, d = threadIdx.x;
  int zz = z[nd], tt = tptr[0], st = sptr[0];
  cat[d] = embed[zz * HSZ + d];
  cat[128 + d] = tT[tt * HSZ + d];
  cat[256 + d] = tH[st * HSZ + d];
  __syncthreads();
  float a = b1[d];
  for (int c = 0; c < 384; c++) a += cat[c] * W1[c * HSZ + d];
  h[d] = fmaxf(a, 0.f);
  __syncthreads();
  a = b2[d];
  for (int c = 0; c < 128; c++) a += h[c] * W2[c * HSZ + d];
  nsc[nd * HSZ + d] = a;
  x0[nd * HSZ + d] = a;
  float* xr = x + (size_t)nd * XSZ + d * NSH;
  xr[0] = a;
  for (int k = 1; k < NSH; k++) xr[k] = 0.f;
}

// ---------------- dst-bucket sort ----------------
__global__ __launch_bounds__(256) void qh_zero(int* counts) {
  int i = blockIdx.x * 256 + threadIdx.x;
  if (i < NN) counts[i] = 0;
}
__global__ __launch_bounds__(256) void qh_count(const int* __restrict__ ei, int* counts) {
  int e = blockIdx.x * 256 + threadIdx.x;
  if (e < NE) atomicAdd(&counts[ei[NE + e]], 1);
}
__global__ __launch_bounds__(1024) void qh_scan(const int* __restrict__ counts,
                                                int* starts, int* cursor) {
  __shared__ int tmp[NN];
  int t = threadIdx.x;
  tmp[t] = counts[t];
  __syncthreads();
  for (int ofs = 1; ofs < NN; ofs <<= 1) {
    int v = (t >= ofs) ? tmp[t - ofs] : 0;
    __syncthreads();
    tmp[t] += v;
    __syncthreads();
  }
  starts[t + 1] = tmp[t];
  if (t == 0) starts[0] = 0;
  cursor[t] = (t == 0) ? 0 : tmp[t - 1];
}
__global__ __launch_bounds__(256) void qh_scatter(const int* __restrict__ ei,
                                                  int* cursor, int* perm) {
  int e = blockIdx.x * 256 + threadIdx.x;
  if (e < NE) {
    int d = ei[NE + e];
    int pos = atomicAdd(&cursor[d], 1);
    perm[pos] = e;
  }
}

// ---------------- radial MLP ----------------
__global__ __launch_bounds__(128) void qh_rad(
    const float* __restrict__ rbf,
    const float* __restrict__ W1, const float* __restrict__ b1,
    const float* __restrict__ W2, const float* __restrict__ b2,
    const float* __restrict__ W3, const float* __restrict__ b3,
    float* __restrict__ wrad) {
  __shared__ float w1l[32 * 64], w2l[64 * 64], w3l[64 * 128];
  __shared__ float rl[32], h1[64], h2[64];
  int t = threadIdx.x;
  for (int i = t; i < 32 * 64; i += 128) w1l[i] = W1[i];
  for (int i = t; i < 64 * 64; i += 128) w2l[i] = W2[i];
  for (int i = t; i < 64 * 128; i += 128) w3l[i] = W3[i];
  float b3t = b3[t];
  float b1t = (t < 64) ? b1[t] : 0.f;
  float b2t = (t < 64) ? b2[t] : 0.f;
  __syncthreads();
  int e0 = blockIdx.x * 16;
  for (int ee = 0; ee < 16; ee++) {
    int e = e0 + ee;
    if (t < 32) rl[t] = rbf[(size_t)e * NRBF + t];
    __syncthreads();
    if (t < 64) {
      float a = b1t;
      for (int c = 0; c < 32; c++) a += rl[c] * w1l[c * 64 + t];
      h1[t] = siluf(a);
    }
    __syncthreads();
    if (t < 64) {
      float a = b2t;
      for (int c = 0; c < 64; c++) a += h1[c] * w2l[c * 64 + t];
      h2[t] = siluf(a);
    }
    __syncthreads();
    float a = b3t;
    for (int c = 0; c < 64; c++) a += h2[c] * w3l[c * 128 + t];
    wrad[(size_t)e * HSZ + t] = a;
    __syncthreads();
  }
}

// ---------------- q/k projections ----------------
__global__ __launch_bounds__(256) void qh_qk(
    const float* __restrict__ x0, const float* __restrict__ Wq, const float* __restrict__ Wk,
    float* __restrict__ q, float* __restrict__ kk) {
  __shared__ float xl[128];
  int nd = blockIdx.x, t = threadIdx.x;
  if (t < 128) xl[t] = x0[nd * HSZ + t];
  __syncthreads();
  int d = t & 127;
  const float* W = (t < 128) ? Wq : Wk;
  float a = 0.f;
  for (int c = 0; c < 128; c++) a += xl[c] * W[c * HSZ + d];
  if (t < 128) q[nd * HSZ + d] = a;
  else kk[nd * HSZ + d] = a;
}

// ---------------- edge-parallel attention logits ----------------
__global__ __launch_bounds__(256) void qh_logit(
    const float* __restrict__ q, const float* __restrict__ kk,
    const int* __restrict__ ei, float* __restrict__ logits) {
  int t = threadIdx.x;
  int e = blockIdx.x * 2 + (t >> 7);
  int c = t & 127;
  int s = ei[e], d = ei[NE + e];
  float p = q[d * HSZ + c] * kk[s * HSZ + c];
#pragma unroll
  for (int m = 16; m >= 1; m >>= 1) p += __shfl_xor(p, m);
  if ((c & 31) == 0) logits[e * 4 + (c >> 5)] = p * 0.17677669529663687f;
}

// ---------------- per-node exact softmax -> alpha[e,h] ----------------
__global__ __launch_bounds__(64) void qh_soft(
    const float* __restrict__ logits, const int* __restrict__ starts,
    const int* __restrict__ perm, float* __restrict__ alpha) {
  int nd = blockIdx.x, t = threadIdx.x;
  if (t >= 4) return;
  int jb = starts[nd], je = starts[nd + 1];
  if (jb >= je) return;
  float m = -1e30f;
  for (int j = jb; j < je; j++) m = fmaxf(m, logits[perm[j] * 4 + t]);
  float den = 0.f;
  for (int j = jb; j < je; j++) den += expf(logits[perm[j] * 4 + t] - m);
  float inv = 1.f / (den + 1e-9f);
  for (int j = jb; j < je; j++) {
    int e = perm[j];
    alpha[e * 4 + t] = expf(logits[e * 4 + t] - m) * inv;
  }
}

// ---------------- fused message + attention aggregation (dbuf) ----------------
__global__ __launch_bounds__(256) void qh_msgatt(
    const float* __restrict__ x, const float* __restrict__ Tk,
    const float* __restrict__ wrad, const float* __restrict__ alpha,
    const int* __restrict__ starts, const int* __restrict__ perm,
    const int* __restrict__ ei,
    float* __restrict__ agg, float* __restrict__ att) {
  __shared__ float xs[2][XSZ];
  __shared__ float tkl[2][628];
  __shared__ float wl[2][128];
  int nd = blockIdx.x, t = threadIdx.x;
  int c = t & 127, hf = t >> 7;
  int k0 = hf ? 13 : 0, nk = hf ? 12 : 13;
  float am[13], aa[13];
#pragma unroll
  for (int u = 0; u < 13; u++) { am[u] = 0.f; aa[u] = 0.f; }
  int jb = starts[nd], je = starts[nd + 1];
  float rx[13], rt[3], rw = 0.f;
  if (jb < je) {
    int e = perm[jb], s = ei[e];
#pragma unroll
    for (int u = 0; u < 12; u++) rx[u] = x[(size_t)s * XSZ + t + u * 256];
    if (t < 128) rx[12] = x[(size_t)s * XSZ + t + 3072];
#pragma unroll
    for (int u = 0; u < 2; u++) rt[u] = Tk[(size_t)e * 625 + t + u * 256];
    if (t < 113) rt[2] = Tk[(size_t)e * 625 + t + 512];
    if (t < 128) rw = wrad[(size_t)e * HSZ + t];
#pragma unroll
    for (int u = 0; u < 12; u++) xs[0][t + u * 256] = rx[u];
    if (t < 128) xs[0][t + 3072] = rx[12];
#pragma unroll
    for (int u = 0; u < 2; u++) tkl[0][t + u * 256] = rt[u];
    if (t < 113) tkl[0][t + 512] = rt[2];
    if (t < 128) wl[0][t] = rw;
  }
  __syncthreads();
  for (int j = jb; j < je; j++) {
    int cur = (j - jb) & 1, nxt = cur ^ 1;
    int e = perm[j];
    float al = alpha[e * 4 + (c >> 5)];
    bool more = (j + 1 < je);
    if (more) {  // prefetch next edge into registers (overlaps compute)
      int e2 = perm[j + 1], s2 = ei[e2];
#pragma unroll
      for (int u = 0; u < 12; u++) rx[u] = x[(size_t)s2 * XSZ + t + u * 256];
      if (t < 128) rx[12] = x[(size_t)s2 * XSZ + t + 3072];
#pragma unroll
      for (int u = 0; u < 2; u++) rt[u] = Tk[(size_t)e2 * 625 + t + u * 256];
      if (t < 113) rt[2] = Tk[(size_t)e2 * 625 + t + 512];
      if (t < 128) rw = wrad[(size_t)e2 * HSZ + t];
    }
    float wc = wl[cur][c];
    const float* xr = &xs[cur][c * NSH];
    const float* tb = &tkl[cur][k0];
#pragma unroll
    for (int i = 0; i < NSH; i++) {
      float xv = xr[i];
      float xw = xv * wc;
      const float* tr = tb + i * NSH;
#pragma unroll
      for (int u = 0; u < 13; u++)
        if (u < nk) am[u] += xw * tr[u];
    }
#pragma unroll
    for (int u = 0; u < 13; u++)
      if (u < nk) aa[u] += al * xr[k0 + u];
    __syncthreads();
    if (more) {
#pragma unroll
      for (int u = 0; u < 12; u++) xs[nxt][t + u * 256] = rx[u];
      if (t < 128) xs[nxt][t + 3072] = rx[12];
#pragma unroll
      for (int u = 0; u < 2; u++) tkl[nxt][t + u * 256] = rt[u];
      if (t < 113) tkl[nxt][t + 512] = rt[2];
      if (t < 128) wl[nxt][t] = rw;
    }
    __syncthreads();
  }
  float* ag = agg + (size_t)nd * XSZ + c * NSH + k0;
  float* at = att + (size_t)nd * XSZ + c * NSH + k0;
#pragma unroll
  for (int u = 0; u < 13; u++)
    if (u < nk) { ag[u] = am[u]; at[u] = aa[u]; }
}

// ---------------- y = mix(agg); x = gate(x + y + att) ----------------
__global__ __launch_bounds__(256) void qh_mix(
    const float* __restrict__ agg, const float* __restrict__ att,
    const float* __restrict__ mixW, float* __restrict__ x, float* __restrict__ x0) {
  __shared__ float Wl[8192];
  __shared__ float aggl[XSZ];
  __shared__ float v0l[128];
  int nd = blockIdx.x, t = threadIdx.x;
  for (int i = t; i < XSZ; i += 256) aggl[i] = agg[(size_t)nd * XSZ + i];
  int d = t & 127, hf = t >> 7;
  int k0 = hf ? 13 : 0, nk = hf ? 12 : 13;
  float v[13];
#pragma unroll
  for (int u = 0; u < 13; u++) v[u] = 0.f;
  for (int lb = 0; lb < 5; lb++) {
    int o = lb * lb, sl = 2 * lb + 1;
    for (int ch = 0; ch < 2; ch++) {
      __syncthreads();
      for (int i = t; i < 8192; i += 256) Wl[i] = mixW[lb * 16384 + ch * 8192 + i];
      __syncthreads();
#pragma unroll
      for (int u = 0; u < 13; u++) {
        int m = k0 + u;
        if (u < nk && m >= o && m < o + sl) {
          float a = 0.f;
          for (int cc = 0; cc < 64; cc++) a += aggl[(ch * 64 + cc) * NSH + m] * Wl[cc * 128 + d];
          v[u] += a;
        }
      }
    }
  }
  size_t base = (size_t)nd * XSZ + d * NSH + k0;
#pragma unroll
  for (int u = 0; u < 13; u++)
    if (u < nk) v[u] += x[base + u] + att[base + u];
  if (hf == 0) v0l[d] = v[0];
  __syncthreads();
  float g = 1.f / (1.f + expf(-v0l[d]));
#pragma unroll
  for (int u = 0; u < 13; u++)
    if (u < nk) x[base + u] = v[u] * g;
  if (hf == 0) x0[nd * HSZ + d] = v[0] * g;
}

// ---------------- per-node output precompute + H_ii ----------------
// fm[n][d][m] = sum_c x[n,c,m]*Wij[lb(m)][c,d];  awb[n][0:32]=nsc@pij_top,
// awb[n][32:64]=nsc@pij_bot;  H_ii folded in via Wii/path_ii.
__global__ __launch_bounds__(256) void qh_prep(
    const float* __restrict__ x, const float* __restrict__ nsc,
    const float* __restrict__ Wii, const float* __restrict__ Wij,
    const float* __restrict__ pii, const float* __restrict__ pij,
    const float* __restrict__ EXPc,
    float* __restrict__ fm, float* __restrict__ awb, float* __restrict__ out) {
  __shared__ float xl[XSZ];
  __shared__ float nl[128];
  __shared__ float wc[4096];
  __shared__ float fml[800];
  __shared__ float wiil[32];
  __shared__ float gl[25];
  int nd = blockIdx.x, t = threadIdx.x;
  for (int i = t; i < XSZ; i += 256) xl[i] = x[(size_t)nd * XSZ + i];
  if (t < 128) nl[t] = nsc[nd * HSZ + t];
  __syncthreads();
  if (t < 32) {
    float a = 0.f;
    for (int cc = 0; cc < 128; cc++) a += nl[cc] * pii[cc * 32 + t];
    wiil[t] = a;
  } else if (t < 96) {
    int d = (t - 32) & 31;
    int half = (t - 32) >> 5;
    const float* pp = pij + (half ? 128 * 32 : 0);
    float a = 0.f;
    for (int cc = 0; cc < 128; cc++) a += nl[cc] * pp[cc * 32 + d];
    awb[nd * 64 + half * 32 + d] = a;
  }
  // fmii (in LDS)
  for (int lb = 0; lb < 5; lb++) {
    __syncthreads();
    for (int i = t; i < 4096; i += 256) wc[i] = Wii[lb * 4096 + i];
    __syncthreads();
    int o = lb * lb, sl = 2 * lb + 1;
    for (int idx = t; idx < 32 * sl; idx += 256) {
      int d = idx & 31, m = o + (idx >> 5);
      float a = 0.f;
      for (int cc = 0; cc < 128; cc++) a += xl[cc * NSH + m] * wc[cc * 32 + d];
      fml[d * NSH + m] = a;
    }
  }
  __syncthreads();
  if (t < 25) {
    float a = 0.f;
#pragma unroll
    for (int d = 0; d < 32; d++) a += wiil[d] * fml[d * NSH + t];
    gl[t] = a;
  }
  __syncthreads();
  if (t < 196) {
    float a = 0.f;
#pragma unroll
    for (int m = 0; m < 25; m++) a += gl[m] * EXPc[m * 196 + t];
    out[(size_t)nd * 196 + t] = a;
  }
  // fmij (to global)
  for (int lb = 0; lb < 5; lb++) {
    __syncthreads();
    for (int i = t; i < 4096; i += 256) wc[i] = Wij[lb * 4096 + i];
    __syncthreads();
    int o = lb * lb, sl = 2 * lb + 1;
    for (int idx = t; idx < 32 * sl; idx += 256) {
      int d = idx & 31, m = o + (idx >> 5);
      float a = 0.f;
      for (int cc = 0; cc < 128; cc++) a += xl[cc * NSH + m] * wc[cc * 32 + d];
      fm[(size_t)nd * 800 + d * NSH + m] = a;
    }
  }
}

// ---------------- H_ij per edge (factorized) ----------------
__global__ __launch_bounds__(256) void qh_fij2(
    const int* __restrict__ ei, const float* __restrict__ fm,
    const float* __restrict__ awb, const float* __restrict__ EXPc,
    float* __restrict__ out) {
  __shared__ float fsum[800], wsum[32], gl[25];
  int e = blockIdx.x, t = threadIdx.x;
  int s = ei[e], d2 = ei[NE + e];
  for (int i = t; i < 800; i += 256)
    fsum[i] = fm[(size_t)s * 800 + i] + fm[(size_t)d2 * 800 + i];
  if (t < 32) wsum[t] = awb[s * 64 + t] + awb[d2 * 64 + 32 + t];
  __syncthreads();
  if (t < 25) {
    float a = 0.f;
#pragma unroll
    for (int d = 0; d < 32; d++) a += wsum[d] * fsum[d * NSH + t];
    gl[t] = a;
  }
  __syncthreads();
  if (t < 196) {
    float a = 0.f;
#pragma unroll
    for (int m = 0; m < 25; m++) a += gl[m] * EXPc[m * 196 + t];
    out[HII_SZ + (size_t)e * 196 + t] = a;
  }
}

// =====================================================================
extern "C" void kernel_launch(void* const* d_in, const int* in_sizes, int n_in,
                              void* d_out, int out_size, void* d_ws, size_t ws_size,
                              hipStream_t stream) {
  (void)in_sizes; (void)n_in; (void)out_size;
  if (ws_size < NEED_BYTES) return;

  const int*   z    = (const int*)d_in[0];
  const float* pos  = (const float*)d_in[1];
  const int*   ei   = (const int*)d_in[2];
  const int*   tptr = (const int*)d_in[4];
  const int*   sptr = (const int*)d_in[5];
  const float* embed= (const float*)d_in[6];
  const float* tT   = (const float*)d_in[7];
  const float* tH   = (const float*)d_in[8];
  const float* sW1  = (const float*)d_in[9];
  const float* sb1  = (const float*)d_in[10];
  const float* sW2  = (const float*)d_in[11];
  const float* sb2  = (const float*)d_in[12];
  const float* rW1  = (const float*)d_in[13];
  const float* rb1  = (const float*)d_in[14];
  const float* rW2  = (const float*)d_in[15];
  const float* rb2  = (const float*)d_in[16];
  const float* rW3  = (const float*)d_in[17];
  const float* rb3  = (const float*)d_in[18];
  const float* mixW = (const float*)d_in[19];
  const float* Wq   = (const float*)d_in[20];
  const float* Wk   = (const float*)d_in[21];
  const float* Wii  = (const float*)d_in[22];
  const float* Wij  = (const float*)d_in[23];
  const float* pii  = (const float*)d_in[24];
  const float* pij  = (const float*)d_in[25];

  float* ws = (float*)d_ws;
  float* CGd   = ws + OFF_CONSTS;
  float* EXPd  = CGd + 15625;
  float* LBNd  = CGd + 15625 + 4900;
  float* x     = ws + OFF_X;
  float* agg   = ws + OFF_AGG;
  float* att   = ws + OFF_ATT;
  float* x0    = ws + OFF_X0;
  float* nsc   = ws + OFF_NSC;
  float* qarr  = ws + OFF_Q;
  float* karr  = ws + OFF_K;
  float* rbf   = ws + OFF_RBF;
  float* sh    = ws + OFF_SH;
  float* Tk    = ws + OFF_TK;
  float* wrad  = ws + OFF_WRAD;
  // aliases onto dead regions:
  float* logits = ws + OFF_SH;            // after qh_tk, sh is dead
  float* alphaA = ws + OFF_SH + 65536;
  float* fm     = ws + OFF_AGG;           // after layer loop, agg is dead
  float* awb    = ws + OFF_AGG + 819200;
  int* ibase   = (int*)(ws + OFF_INT);
  int* counts  = ibase;
  int* starts  = ibase + 1024;
  int* cursor  = ibase + 1024 + 1025;
  int* perm    = ibase + 1024 + 1025 + 1024;
  float* outp  = (float*)d_out;

  hipMemcpyAsync(CGd, qhc::g_hc.buf, 20557 * sizeof(float), hipMemcpyHostToDevice, stream);

  qh_geom<<<NE / 256, 256, 0, stream>>>(pos, ei, LBNd, rbf, sh);
  qh_tk<<<NE / 32, 256, 0, stream>>>(sh, CGd, Tk);
  qh_nsc<<<NN, 128, 0, stream>>>(z, tptr, sptr, embed, tT, tH, sW1, sb1, sW2, sb2, nsc, x, x0);
  qh_zero<<<NN / 256, 256, 0, stream>>>(counts);
  qh_count<<<NE / 256, 256, 0, stream>>>(ei, counts);
  qh_scan<<<1, 1024, 0, stream>>>(counts, starts, cursor);
  qh_scatter<<<NE / 256, 256, 0, stream>>>(ei, cursor, perm);

  for (int l = 0; l < NLAY; l++) {
    qh_rad<<<NE / 16, 128, 0, stream>>>(rbf,
        rW1 + (size_t)l * 32 * 64, rb1 + (size_t)l * 64,
        rW2 + (size_t)l * 64 * 64, rb2 + (size_t)l * 64,
        rW3 + (size_t)l * 64 * 128, rb3 + (size_t)l * 128, wrad);
    qh_qk<<<NN, 256, 0, stream>>>(x0, Wq + (size_t)l * 16384, Wk + (size_t)l * 16384, qarr, karr);
    qh_logit<<<NE / 2, 256, 0, stream>>>(qarr, karr, ei, logits);
    qh_soft<<<NN, 64, 0, stream>>>(logits, starts, perm, alphaA);
    qh_msgatt<<<NN, 256, 0, stream>>>(x, Tk, wrad, alphaA, starts, perm, ei, agg, att);
    qh_mix<<<NN, 256, 0, stream>>>(agg, att, mixW + (size_t)l * 81920, x, x0);
  }

  qh_prep<<<NN, 256, 0, stream>>>(x, nsc, Wii, Wij, pii, pij, EXPd, fm, awb, outp);
  qh_fij2<<<NE, 256, 0, stream>>>(ei, fm, awb, EXPd, outp);
}

// Round 5
// 1485.567 us; speedup vs baseline: 2.1053x; 1.2752x over previous
//
#include <hip/hip_runtime.h>
#include <cstdint>
#include <cmath>
#include <cstddef>

// ---------------- problem constants ----------------
constexpr int NN   = 1024;     // nodes
constexpr int NE   = 16384;    // edges
constexpr int HSZ  = 128;      // hidden size
constexpr int NSH  = 25;       // spherical harmonics (l<=4)
constexpr int NRBF = 32;
constexpr int NLAY = 5;
constexpr int XSZ  = HSZ * NSH;   // 3200
constexpr int HII_SZ = NN * 196;  // 200704

// x/agg/att layout: [n][m][c]  (element (n,m,c) at n*3200 + m*128 + c)

// ---------------- ws layout (float offsets) ----------------
constexpr size_t OFF_CONSTS = 0;  // CG 15625 | EXP 4900 | logbinom 32  (20557, pad 20560)
constexpr size_t OFF_X    = 20560;
constexpr size_t OFF_AGG  = OFF_X    + (size_t)NN * XSZ;
constexpr size_t OFF_ATT  = OFF_AGG  + (size_t)NN * XSZ;
constexpr size_t OFF_X0   = OFF_ATT  + (size_t)NN * XSZ;
constexpr size_t OFF_NSC  = OFF_X0   + (size_t)NN * HSZ;
constexpr size_t OFF_Q    = OFF_NSC  + (size_t)NN * HSZ;
constexpr size_t OFF_K    = OFF_Q    + (size_t)NN * HSZ;
constexpr size_t OFF_RBF  = OFF_K    + (size_t)NN * HSZ;
constexpr size_t OFF_SH   = OFF_RBF  + (size_t)NE * NRBF;
constexpr size_t OFF_TK   = OFF_SH   + (size_t)NE * NSH;
constexpr size_t OFF_WRAD = OFF_TK   + (size_t)NE * NSH * NSH;
constexpr size_t OFF_INT  = OFF_WRAD + (size_t)NE * HSZ;   // ints start here
constexpr size_t NEED_BYTES = OFF_INT * 4 + (size_t)(1024 + 1025 + 1024 + 16384) * 4;
// aliases: logits->OFF_SH (65536) | alpha->OFF_SH+65536 | fm->OFF_AGG | awb->OFF_AGG+819200

// =====================================================================
// Host-side reproduction of np.random.default_rng(7) (verified round 3).
// =====================================================================
namespace qhc {

struct Pcg64 {
  unsigned __int128 state, inc;
  static unsigned __int128 mult() {
    return (((unsigned __int128)2549297995355413924ULL) << 64) | 4865540595714422341ULL;
  }
  void step() { state = state * mult() + inc; }
  uint64_t next64() {
    step();
    uint64_t hi = (uint64_t)(state >> 64), lo = (uint64_t)state;
    uint64_t x = hi ^ lo;
    unsigned rot = (unsigned)(state >> 122);
    return (x >> rot) | (x << ((64u - rot) & 63u));
  }
  double nextd() { return (double)(next64() >> 11) * (1.0 / 9007199254740992.0); }
};

struct HostConsts {
  float buf[20560];
  HostConsts() {
    const uint32_t INIT_A = 0x43b0d7e5u, MULT_A = 0x931e8875u;
    const uint32_t INIT_B = 0x8b51f9ddu, MULT_B = 0x58f38dedu;
    uint32_t pool[4];
    uint32_t hc = INIT_A;
    auto hashf = [&](uint32_t v) -> uint32_t {
      v ^= hc; hc *= MULT_A; v *= hc; v ^= v >> 16; return v;
    };
    auto mixf = [](uint32_t x, uint32_t y) -> uint32_t {
      uint32_t r = x * 0xca01f9ddu - y * 0x4973f715u;
      r ^= r >> 16;
      return r;
    };
    pool[0] = hashf(7u);
    for (int i = 1; i < 4; i++) pool[i] = hashf(0u);
    for (int s = 0; s < 4; s++)
      for (int d = 0; d < 4; d++)
        if (s != d) pool[d] = mixf(pool[d], hashf(pool[s]));
    uint32_t st32[8];
    uint32_t hb = INIT_B;
    for (int i = 0; i < 8; i++) {
      uint32_t v = pool[i % 4];
      v ^= hb; hb *= MULT_B; v *= hb; v ^= v >> 16;
      st32[i] = v;
    }
    uint64_t w0 = st32[0] | ((uint64_t)st32[1] << 32);
    uint64_t w1 = st32[2] | ((uint64_t)st32[3] << 32);
    uint64_t w2 = st32[4] | ((uint64_t)st32[5] << 32);
    uint64_t w3 = st32[6] | ((uint64_t)st32[7] << 32);
    unsigned __int128 seed = (((unsigned __int128)w0) << 64) | w1;
    unsigned __int128 incs = (((unsigned __int128)w2) << 64) | w3;
    Pcg64 g;
    g.state = 0; g.inc = (incs << 1) | 1;
    g.step(); g.state += seed; g.step();
    double wi[256], fi[256]; uint64_t ki[256];
    {
      const double m1 = 4503599627370496.0;
      double dn = 3.6541528853610087963519472518, tn = dn, vn = 0.00492867323399941;
      double q = vn / std::exp(-0.5 * dn * dn);
      ki[0] = (uint64_t)((dn / q) * m1); ki[1] = 0;
      wi[0] = q / m1; wi[255] = dn / m1;
      fi[0] = 1.0; fi[255] = std::exp(-0.5 * dn * dn);
      for (int i = 254; i >= 1; i--) {
        dn = std::sqrt(-2.0 * std::log(vn / dn + std::exp(-0.5 * dn * dn)));
        ki[i + 1] = (uint64_t)((dn / tn) * m1);
        tn = dn;
        fi[i] = std::exp(-0.5 * dn * dn);
        wi[i] = dn / m1;
      }
    }
    const double ZR = 3.6541528853610087963519472518;
    const double ZIR = 0.27366123732975827203338247596;
    auto stdnorm = [&]() -> double {
      for (;;) {
        uint64_t r = g.next64();
        int idx = (int)(r & 0xff);
        r >>= 8;
        int sign = (int)(r & 1);
        uint64_t rabs = (r >> 1) & 0x000fffffffffffffULL;
        double xv = (double)rabs * wi[idx];
        if (sign) xv = -xv;
        if (rabs < ki[idx]) return xv;
        if (idx == 0) {
          for (;;) {
            double xx = -ZIR * std::log1p(-g.nextd());
            double yy = -std::log1p(-g.nextd());
            if (yy + yy > xx * xx)
              return ((rabs >> 8) & 1) ? -(ZR + xx) : (ZR + xx);
          }
        } else {
          if (((fi[idx - 1] - fi[idx]) * g.nextd() + fi[idx]) < std::exp(-0.5 * xv * xv))
            return xv;
        }
      }
    };
    for (int i = 0; i < 15625 + 4900; i++) buf[i] = (float)(0.1 * stdnorm());
    double logf[32]; logf[0] = 0.0;
    for (int i = 1; i < 32; i++) logf[i] = logf[i - 1] + std::log((double)i);
    for (int k = 0; k < 32; k++) buf[15625 + 4900 + k] = (float)(logf[31] - logf[k] - logf[31 - k]);
    buf[20557] = buf[20558] = buf[20559] = 0.f;
  }
};
static HostConsts g_hc;
}  // namespace qhc

// =====================================================================
__device__ __forceinline__ float siluf(float a) { return a / (1.f + expf(-a)); }

// ---------------- edge geometry: sh + rbf ----------------
__global__ __launch_bounds__(256) void qh_geom(
    const float* __restrict__ pos, const int* __restrict__ ei,
    const float* __restrict__ lbn, float* __restrict__ rbf, float* __restrict__ sh) {
  int e = blockIdx.x * 256 + threadIdx.x;
  if (e >= NE) return;
  int s = ei[e], d = ei[NE + e];
  float vx = pos[s * 3 + 0] - pos[d * 3 + 0];
  float vy = pos[s * 3 + 1] - pos[d * 3 + 1];
  float vz = pos[s * 3 + 2] - pos[d * 3 + 2];
  float r = sqrtf(vx * vx + vy * vy + vz * vz + 1e-12f);
  float inv = 1.0f / r;
  float x = vx * inv, y = vy * inv, z = vz * inv;
  float x2 = x * x, y2 = y * y, z2 = z * z;
  float* sp = sh + (size_t)e * NSH;
  sp[0] = 0.282095f;
  sp[1] = 0.488603f * y;
  sp[2] = 0.488603f * z;
  sp[3] = 0.488603f * x;
  sp[4] = 1.092548f * x * y;
  sp[5] = 1.092548f * y * z;
  sp[6] = 0.315392f * (3.f * z2 - 1.f);
  sp[7] = 1.092548f * x * z;
  sp[8] = 0.546274f * (x2 - y2);
  sp[9] = 0.590044f * y * (3.f * x2 - y2);
  sp[10] = 2.890611f * x * y * z;
  sp[11] = 0.457046f * y * (5.f * z2 - 1.f);
  sp[12] = 0.373176f * z * (5.f * z2 - 3.f);
  sp[13] = 0.457046f * x * (5.f * z2 - 1.f);
  sp[14] = 1.445306f * z * (x2 - y2);
  sp[15] = 0.590044f * x * (x2 - 3.f * y2);
  sp[16] = 2.503343f * x * y * (x2 - y2);
  sp[17] = 1.770131f * y * z * (3.f * x2 - y2);
  sp[18] = 0.946175f * x * y * (7.f * z2 - 1.f);
  sp[19] = 0.669047f * y * z * (7.f * z2 - 3.f);
  sp[20] = 0.105786f * (35.f * z2 * z2 - 30.f * z2 + 3.f);
  sp[21] = 0.669047f * x * z * (7.f * z2 - 3.f);
  sp[22] = 0.473087f * (x2 - y2) * (7.f * z2 - 1.f);
  sp[23] = 1.770131f * x * z * (x2 - 3.f * y2);
  sp[24] = 0.625836f * (x2 * x2 - 6.f * x2 * y2 + y2 * y2);
  float xr = expf(-0.5f * r);
  float l1 = log1pf(-xr + 1e-7f);
  float fc = 0.5f * (cosf(3.14159265358979323846f * fminf(r * (1.0f / 12.0f), 1.0f)) + 1.0f);
  float* rp = rbf + (size_t)e * NRBF;
  for (int k = 0; k < NRBF; k++) {
    float b = expf(lbn[k] + (float)k * (-0.5f * r) + (float)(NRBF - 1 - k) * l1);
    rp[k] = b * fc;
  }
}

// ---------------- Tk[e][i*25+k] = sum_j sh[e,j]*CG[i,j,k] ----------------
__global__ __launch_bounds__(256) void qh_tk(
    const float* __restrict__ sh, const float* __restrict__ CG, float* __restrict__ Tk) {
  __shared__ float shl[32 * NSH];
  int e0 = blockIdx.x * 32;
  int t = threadIdx.x;
  for (int i = t; i < 32 * NSH; i += 256) shl[i] = sh[(size_t)e0 * NSH + i];
  __syncthreads();
  for (int ik = t; ik < NSH * NSH; ik += 256) {
    int i = ik / NSH, k = ik % NSH;
    float cg[NSH];
#pragma unroll
    for (int j = 0; j < NSH; j++) cg[j] = CG[i * 625 + j * NSH + k];
    for (int ee = 0; ee < 32; ee++) {
      float acc = 0.f;
#pragma unroll
      for (int j = 0; j < NSH; j++) acc += shl[ee * NSH + j] * cg[j];
      Tk[(size_t)(e0 + ee) * 625 + ik] = acc;
    }
  }
}

// ---------------- node scalar MLP + init x ([m][c] layout) ----------------
__global__ __launch_bounds__(128) void qh_nsc(
    const int* __restrict__ z, const int* __restrict__ tptr, const int* __restrict__ sptr,
    const float* __restrict__ embed, const float* __restrict__ tT, const float* __restrict__ tH,
    const float* __restrict__ W1, const float* __restrict__ b1,
    const float* __restrict__ W2, const float* __restrict__ b2,
    float* __restrict__ nsc, float* __restrict__ x, float* __restrict__ x0) {
  __shared__ float cat[384];
  __shared__ float h[128];
  int nd = blockIdx.x, d = threadIdx.x;
  int zz = z[nd], tt = tptr[0], st = sptr[0];
  cat[d] = embed[zz * HSZ + d];
  cat[128 + d] = tT[tt * HSZ + d];
  cat[256 + d] = tH[st * HSZ + d];
  __syncthreads();
  float a = b1[d];
  for (int c = 0; c < 384; c++) a += cat[c] * W1[c * HSZ + d];
  h[d] = fmaxf(a, 0.f);
  __syncthreads();
  a = b2[d];
  for (int c = 0; c < 128; c++) a += h[c] * W2[c * HSZ + d];
  nsc[nd * HSZ + d] = a;
  x0[nd * HSZ + d] = a;
  float* xr = x + (size_t)nd * XSZ + d;
  xr[0] = a;                       // m=0
  for (int m = 1; m < NSH; m++) xr[m * 128] = 0.f;
}

// ---------------- dst-bucket sort ----------------
__global__ __launch_bounds__(256) void qh_zero(int* counts) {
  int i = blockIdx.x * 256 + threadIdx.x;
  if (i < NN) counts[i] = 0;
}
__global__ __launch_bounds__(256) void qh_count(const int* __restrict__ ei, int* counts) {
  int e = blockIdx.x * 256 + threadIdx.x;
  if (e < NE) atomicAdd(&counts[ei[NE + e]], 1);
}
__global__ __launch_bounds__(1024) void qh_scan(const int* __restrict__ counts,
                                                int* starts, int* cursor) {
  __shared__ int tmp[NN];
  int t = threadIdx.x;
  tmp[t] = counts[t];
  __syncthreads();
  for (int ofs = 1; ofs < NN; ofs <<= 1) {
    int v = (t >= ofs) ? tmp[t - ofs] : 0;
    __syncthreads();
    tmp[t] += v;
    __syncthreads();
  }
  starts[t + 1] = tmp[t];
  if (t == 0) starts[0] = 0;
  cursor[t] = (t == 0) ? 0 : tmp[t - 1];
}
__global__ __launch_bounds__(256) void qh_scatter(const int* __restrict__ ei,
                                                  int* cursor, int* perm) {
  int e = blockIdx.x * 256 + threadIdx.x;
  if (e < NE) {
    int d = ei[NE + e];
    int pos = atomicAdd(&cursor[d], 1);
    perm[pos] = e;
  }
}

// ---------------- radial MLP: 16 edges/block, 4-edge-parallel phases ----------------
__global__ __launch_bounds__(256) void qh_rad(
    const float* __restrict__ rbf,
    const float* __restrict__ W1, const float* __restrict__ b1,
    const float* __restrict__ W2, const float* __restrict__ b2,
    const float* __restrict__ W3, const float* __restrict__ b3,
    float* __restrict__ wrad) {
  __shared__ float w1l[2048], w2l[4096], w3l[8192];
  __shared__ float rl[4][32], h1[4][64], h2[4][64];
  int t = threadIdx.x;
  for (int i = t; i < 2048; i += 256) w1l[i] = W1[i];
  for (int i = t; i < 4096; i += 256) w2l[i] = W2[i];
  for (int i = t; i < 8192; i += 256) w3l[i] = W3[i];
  __syncthreads();
  int e0 = blockIdx.x * 16;
  for (int q = 0; q < 4; q++) {
    int eb = e0 + q * 4;
    if (t < 128) rl[t >> 5][t & 31] = rbf[(size_t)(eb + (t >> 5)) * NRBF + (t & 31)];
    __syncthreads();
    {
      int eg = t >> 6, u = t & 63;
      float a = b1[u];
      for (int c = 0; c < 32; c++) a += rl[eg][c] * w1l[c * 64 + u];
      h1[eg][u] = siluf(a);
    }
    __syncthreads();
    {
      int eg = t >> 6, u = t & 63;
      float a = b2[u];
      for (int c = 0; c < 64; c++) a += h1[eg][c] * w2l[c * 64 + u];
      h2[eg][u] = siluf(a);
    }
    __syncthreads();
#pragma unroll
    for (int p = 0; p < 2; p++) {
      int eg = (t >> 7) + p * 2, u = t & 127;
      float a = b3[u];
      for (int c = 0; c < 64; c++) a += h2[eg][c] * w3l[c * 128 + u];
      wrad[(size_t)(eb + eg) * HSZ + u] = a;
    }
    __syncthreads();
  }
}

// ---------------- q/k projections ----------------
__global__ __launch_bounds__(256) void qh_qk(
    const float* __restrict__ x0, const float* __restrict__ Wq, const float* __restrict__ Wk,
    float* __restrict__ q, float* __restrict__ kk) {
  __shared__ float xl[128];
  int nd = blockIdx.x, t = threadIdx.x;
  if (t < 128) xl[t] = x0[nd * HSZ + t];
  __syncthreads();
  int d = t & 127;
  const float* W = (t < 128) ? Wq : Wk;
  float a = 0.f;
  for (int c = 0; c < 128; c++) a += xl[c] * W[c * HSZ + d];
  if (t < 128) q[nd * HSZ + d] = a;
  else kk[nd * HSZ + d] = a;
}

// ---------------- edge-parallel attention logits ----------------
__global__ __launch_bounds__(256) void qh_logit(
    const float* __restrict__ q, const float* __restrict__ kk,
    const int* __restrict__ ei, float* __restrict__ logits) {
  int t = threadIdx.x;
  int e = blockIdx.x * 2 + (t >> 7);
  int c = t & 127;
  int s = ei[e], d = ei[NE + e];
  float p = q[d * HSZ + c] * kk[s * HSZ + c];
#pragma unroll
  for (int m = 16; m >= 1; m >>= 1) p += __shfl_xor(p, m);
  if ((c & 31) == 0) logits[e * 4 + (c >> 5)] = p * 0.17677669529663687f;
}

// ---------------- per-node exact softmax (16 lanes per head) ----------------
__global__ __launch_bounds__(64) void qh_soft(
    const float* __restrict__ logits, const int* __restrict__ starts,
    const int* __restrict__ perm, float* __restrict__ alpha) {
  int nd = blockIdx.x, t = threadIdx.x;
  int hh = t >> 4, l = t & 15;
  int jb = starts[nd], je = starts[nd + 1];
  float m = -1e30f;
  for (int j = jb + l; j < je; j += 16) m = fmaxf(m, logits[perm[j] * 4 + hh]);
#pragma unroll
  for (int s = 1; s < 16; s <<= 1) m = fmaxf(m, __shfl_xor(m, s));
  float den = 0.f;
  for (int j = jb + l; j < je; j += 16) den += expf(logits[perm[j] * 4 + hh] - m);
#pragma unroll
  for (int s = 1; s < 16; s <<= 1) den += __shfl_xor(den, s);
  float inv = 1.f / (den + 1e-9f);
  for (int j = jb + l; j < je; j += 16) {
    int e = perm[j];
    alpha[e * 4 + hh] = expf(logits[e * 4 + hh] - m) * inv;
  }
}

// ---------------- fused message + attention agg (channel-split, dbuf) ----------------
// 2 blocks/node: block handles 64 channels; 18.5 KB LDS -> 8 blocks/CU.
__global__ __launch_bounds__(256) void qh_msgatt(
    const float* __restrict__ x, const float* __restrict__ Tk,
    const float* __restrict__ wrad, const float* __restrict__ alpha,
    const int* __restrict__ starts, const int* __restrict__ perm,
    const int* __restrict__ ei,
    float* __restrict__ agg, float* __restrict__ att) {
  __shared__ float xs[2][1600];   // [m][cl] 25 x 64
  __shared__ float tkl[2][628];
  __shared__ float wl[2][64];
  int nd = blockIdx.x >> 1, h = blockIdx.x & 1;
  int t = threadIdx.x;
  int cl = t & 63, q4 = t >> 6;          // q4 wave-uniform
  int c = h * 64 + cl;
  int k0 = (q4 == 0) ? 0 : (1 + 6 * q4); // {0,7,13,19}
  int nk = (q4 == 0) ? 7 : 6;
  float am[7], aa[7];
#pragma unroll
  for (int u = 0; u < 7; u++) { am[u] = 0.f; aa[u] = 0.f; }
  int jb = starts[nd], je = starts[nd + 1];
  float rx[7], rt[3], rw = 0.f;
  if (jb < je) {
    int e = perm[jb], s = ei[e];
#pragma unroll
    for (int u = 0; u < 6; u++) {
      int i = t + u * 256;
      rx[u] = x[(size_t)s * XSZ + (i >> 6) * 128 + h * 64 + (i & 63)];
    }
    if (t < 64) rx[6] = x[(size_t)s * XSZ + 24 * 128 + h * 64 + t];
    rt[0] = Tk[(size_t)e * 625 + t];
    rt[1] = Tk[(size_t)e * 625 + 256 + t];
    if (t < 113) rt[2] = Tk[(size_t)e * 625 + 512 + t];
    if (t < 64) rw = wrad[(size_t)e * HSZ + h * 64 + t];
#pragma unroll
    for (int u = 0; u < 6; u++) xs[0][t + u * 256] = rx[u];
    if (t < 64) xs[0][1536 + t] = rx[6];
    tkl[0][t] = rt[0];
    tkl[0][256 + t] = rt[1];
    if (t < 113) tkl[0][512 + t] = rt[2];
    if (t < 64) wl[0][t] = rw;
  }
  __syncthreads();
  for (int j = jb; j < je; j++) {
    int cur = (j - jb) & 1, nxt = cur ^ 1;
    int e = perm[j];
    float al = alpha[e * 4 + (c >> 5)];
    bool more = (j + 1 < je);
    if (more) {  // register prefetch overlaps compute
      int e2 = perm[j + 1], s2 = ei[e2];
#pragma unroll
      for (int u = 0; u < 6; u++) {
        int i = t + u * 256;
        rx[u] = x[(size_t)s2 * XSZ + (i >> 6) * 128 + h * 64 + (i & 63)];
      }
      if (t < 64) rx[6] = x[(size_t)s2 * XSZ + 24 * 128 + h * 64 + t];
      rt[0] = Tk[(size_t)e2 * 625 + t];
      rt[1] = Tk[(size_t)e2 * 625 + 256 + t];
      if (t < 113) rt[2] = Tk[(size_t)e2 * 625 + 512 + t];
      if (t < 64) rw = wrad[(size_t)e2 * HSZ + h * 64 + t];
    }
    float wc = wl[cur][cl];
#pragma unroll
    for (int i = 0; i < NSH; i++) {
      float xw = xs[cur][i * 64 + cl] * wc;
      const float* tr = &tkl[cur][i * 25 + k0];
#pragma unroll
      for (int u = 0; u < 7; u++)
        if (u < nk) am[u] += xw * tr[u];
    }
#pragma unroll
    for (int u = 0; u < 7; u++)
      if (u < nk) aa[u] += al * xs[cur][(k0 + u) * 64 + cl];
    __syncthreads();
    if (more) {
#pragma unroll
      for (int u = 0; u < 6; u++) xs[nxt][t + u * 256] = rx[u];
      if (t < 64) xs[nxt][1536 + t] = rx[6];
      tkl[nxt][t] = rt[0];
      tkl[nxt][256 + t] = rt[1];
      if (t < 113) tkl[nxt][512 + t] = rt[2];
      if (t < 64) wl[nxt][t] = rw;
    }
    __syncthreads();
  }
#pragma unroll
  for (int u = 0; u < 7; u++)
    if (u < nk) {
      agg[(size_t)nd * XSZ + (k0 + u) * 128 + c] = am[u];
      att[(size_t)nd * XSZ + (k0 + u) * 128 + c] = aa[u];
    }
}

// ---------------- mix as row-GEMM: agg[row] <- agg[row] @ W_lb (in place) ----------------
// 800 blocks: per-lb row tiles of 32 (rows exclusive per block -> in-place safe).
__global__ __launch_bounds__(256) void qh_mixgemm(
    const float* __restrict__ mixW, float* __restrict__ agg) {
  __shared__ float Wl[8192];   // [c][64] current d-half, 32 KB
  __shared__ float Al[4096];   // [32][128], 16 KB
  int b = blockIdx.x, t = threadIdx.x;
  int lb, cum;
  if (b < 32)       { lb = 0; cum = 0; }
  else if (b < 128) { lb = 1; cum = 32; }
  else if (b < 288) { lb = 2; cum = 128; }
  else if (b < 512) { lb = 3; cum = 288; }
  else              { lb = 4; cum = 512; }
  int sl = 2 * lb + 1, o = lb * lb;
  int row0 = (b - cum) * 32;
  const float* W = mixW + lb * 16384;
  for (int i = t; i < 4096; i += 256) {
    int r = i >> 7, cc = i & 127;
    int gr = row0 + r, n = gr / sl, m = o + gr - n * sl;
    Al[i] = agg[(size_t)n * XSZ + m * 128 + cc];
  }
  int dl = t & 63, rg = t >> 6;   // rg 0..3, 8 rows each
  float out[2][8];
  for (int p = 0; p < 2; p++) {
    __syncthreads();
    for (int i = t; i < 8192; i += 256) {
      int cc = i >> 6, d2 = i & 63;
      Wl[i] = W[cc * 128 + p * 64 + d2];
    }
    __syncthreads();
    float acc[8];
#pragma unroll
    for (int r = 0; r < 8; r++) acc[r] = 0.f;
    for (int cc = 0; cc < 128; cc++) {
      float w = Wl[cc * 64 + dl];
#pragma unroll
      for (int r = 0; r < 8; r++) acc[r] += Al[(rg * 8 + r) * 128 + cc] * w;
    }
#pragma unroll
    for (int r = 0; r < 8; r++) out[p][r] = acc[r];
  }
#pragma unroll
  for (int p = 0; p < 2; p++)
#pragma unroll
    for (int r = 0; r < 8; r++) {
      int gr = row0 + rg * 8 + r, n = gr / sl, m = o + gr - n * sl;
      agg[(size_t)n * XSZ + m * 128 + p * 64 + dl] = out[p][r];
    }
}

// ---------------- gate epilogue: x = gate(x + y + att) ----------------
__global__ __launch_bounds__(256) void qh_gate(
    const float* __restrict__ y, const float* __restrict__ att,
    float* __restrict__ x, float* __restrict__ x0) {
  __shared__ float v0l[128];
  int nd = blockIdx.x, t = threadIdx.x;
  int d = t & 127, mh = t >> 7;
  int m0 = mh ? 13 : 0, nm = mh ? 12 : 13;
  float v[13];
  size_t base = (size_t)nd * XSZ + (size_t)m0 * 128 + d;
#pragma unroll
  for (int u = 0; u < 13; u++)
    if (u < nm) v[u] = x[base + (size_t)u * 128] + y[base + (size_t)u * 128] + att[base + (size_t)u * 128];
  if (mh == 0) v0l[d] = v[0];
  __syncthreads();
  float g = 1.f / (1.f + expf(-v0l[d]));
#pragma unroll
  for (int u = 0; u < 13; u++)
    if (u < nm) x[base + (size_t)u * 128] = v[u] * g;   // m=0: v0*g == silu(v0)
  if (mh == 0) x0[nd * HSZ + d] = v[0] * g;
}

// ---------------- per-node output precompute + H_ii ----------------
__global__ __launch_bounds__(256) void qh_prep(
    const float* __restrict__ x, const float* __restrict__ nsc,
    const float* __restrict__ Wii, const float* __restrict__ Wij,
    const float* __restrict__ pii, const float* __restrict__ pij,
    const float* __restrict__ EXPc,
    float* __restrict__ fm, float* __restrict__ awb, float* __restrict__ out) {
  __shared__ float xl[XSZ];
  __shared__ float nl[128];
  __shared__ float wc[4096];
  __shared__ float fml[800];
  __shared__ float wiil[32];
  __shared__ float gl[25];
  int nd = blockIdx.x, t = threadIdx.x;
  for (int i = t; i < XSZ; i += 256) xl[i] = x[(size_t)nd * XSZ + i];
  if (t < 128) nl[t] = nsc[nd * HSZ + t];
  __syncthreads();
  if (t < 32) {
    float a = 0.f;
    for (int cc = 0; cc < 128; cc++) a += nl[cc] * pii[cc * 32 + t];
    wiil[t] = a;
  } else if (t < 96) {
    int d = (t - 32) & 31;
    int half = (t - 32) >> 5;
    const float* pp = pij + (half ? 128 * 32 : 0);
    float a = 0.f;
    for (int cc = 0; cc < 128; cc++) a += nl[cc] * pp[cc * 32 + d];
    awb[nd * 64 + half * 32 + d] = a;
  }
  for (int lb = 0; lb < 5; lb++) {
    __syncthreads();
    for (int i = t; i < 4096; i += 256) wc[i] = Wii[lb * 4096 + i];
    __syncthreads();
    int o = lb * lb, sl = 2 * lb + 1;
    for (int idx = t; idx < 32 * sl; idx += 256) {
      int d = idx & 31, m = o + (idx >> 5);
      float a = 0.f;
      for (int cc = 0; cc < 128; cc++) a += xl[m * 128 + cc] * wc[cc * 32 + d];
      fml[d * NSH + m] = a;
    }
  }
  __syncthreads();
  if (t < 25) {
    float a = 0.f;
#pragma unroll
    for (int d = 0; d < 32; d++) a += wiil[d] * fml[d * NSH + t];
    gl[t] = a;
  }
  __syncthreads();
  if (t < 196) {
    float a = 0.f;
#pragma unroll
    for (int m = 0; m < 25; m++) a += gl[m] * EXPc[m * 196 + t];
    out[(size_t)nd * 196 + t] = a;
  }
  for (int lb = 0; lb < 5; lb++) {
    __syncthreads();
    for (int i = t; i < 4096; i += 256) wc[i] = Wij[lb * 4096 + i];
    __syncthreads();
    int o = lb * lb, sl = 2 * lb + 1;
    for (int idx = t; idx < 32 * sl; idx += 256) {
      int d = idx & 31, m = o + (idx >> 5);
      float a = 0.f;
      for (int cc = 0; cc < 128; cc++) a += xl[m * 128 + cc] * wc[cc * 32 + d];
      fm[(size_t)nd * 800 + d * NSH + m] = a;
    }
  }
}

// ---------------- H_ij per edge (factorized) ----------------
__global__ __launch_bounds__(256) void qh_fij2(
    const int* __restrict__ ei, const float* __restrict__ fm,
    const float* __restrict__ awb, const float* __restrict__ EXPc,
    float* __restrict__ out) {
  __shared__ float fsum[800], wsum[32], gl[25];
  int e = blockIdx.x, t = threadIdx.x;
  int s = ei[e], d2 = ei[NE + e];
  for (int i = t; i < 800; i += 256)
    fsum[i] = fm[(size_t)s * 800 + i] + fm[(size_t)d2 * 800 + i];
  if (t < 32) wsum[t] = awb[s * 64 + t] + awb[d2 * 64 + 32 + t];
  __syncthreads();
  if (t < 25) {
    float a = 0.f;
#pragma unroll
    for (int d = 0; d < 32; d++) a += wsum[d] * fsum[d * NSH + t];
    gl[t] = a;
  }
  __syncthreads();
  if (t < 196) {
    float a = 0.f;
#pragma unroll
    for (int m = 0; m < 25; m++) a += gl[m] * EXPc[m * 196 + t];
    out[HII_SZ + (size_t)e * 196 + t] = a;
  }
}

// =====================================================================
extern "C" void kernel_launch(void* const* d_in, const int* in_sizes, int n_in,
                              void* d_out, int out_size, void* d_ws, size_t ws_size,
                              hipStream_t stream) {
  (void)in_sizes; (void)n_in; (void)out_size;
  if (ws_size < NEED_BYTES) return;

  const int*   z    = (const int*)d_in[0];
  const float* pos  = (const float*)d_in[1];
  const int*   ei   = (const int*)d_in[2];
  const int*   tptr = (const int*)d_in[4];
  const int*   sptr = (const int*)d_in[5];
  const float* embed= (const float*)d_in[6];
  const float* tT   = (const float*)d_in[7];
  const float* tH   = (const float*)d_in[8];
  const float* sW1  = (const float*)d_in[9];
  const float* sb1  = (const float*)d_in[10];
  const float* sW2  = (const float*)d_in[11];
  const float* sb2  = (const float*)d_in[12];
  const float* rW1  = (const float*)d_in[13];
  const float* rb1  = (const float*)d_in[14];
  const float* rW2  = (const float*)d_in[15];
  const float* rb2  = (const float*)d_in[16];
  const float* rW3  = (const float*)d_in[17];
  const float* rb3  = (const float*)d_in[18];
  const float* mixW = (const float*)d_in[19];
  const float* Wq   = (const float*)d_in[20];
  const float* Wk   = (const float*)d_in[21];
  const float* Wii  = (const float*)d_in[22];
  const float* Wij  = (const float*)d_in[23];
  const float* pii  = (const float*)d_in[24];
  const float* pij  = (const float*)d_in[25];

  float* ws = (float*)d_ws;
  float* CGd   = ws + OFF_CONSTS;
  float* EXPd  = CGd + 15625;
  float* LBNd  = CGd + 15625 + 4900;
  float* x     = ws + OFF_X;
  float* agg   = ws + OFF_AGG;
  float* att   = ws + OFF_ATT;
  float* x0    = ws + OFF_X0;
  float* nsc   = ws + OFF_NSC;
  float* qarr  = ws + OFF_Q;
  float* karr  = ws + OFF_K;
  float* rbf   = ws + OFF_RBF;
  float* sh    = ws + OFF_SH;
  float* Tk    = ws + OFF_TK;
  float* wrad  = ws + OFF_WRAD;
  float* logits = ws + OFF_SH;            // sh dead after qh_tk
  float* alphaA = ws + OFF_SH + 65536;
  float* fm     = ws + OFF_AGG;           // agg dead after layer loop
  float* awb    = ws + OFF_AGG + 819200;
  int* ibase   = (int*)(ws + OFF_INT);
  int* counts  = ibase;
  int* starts  = ibase + 1024;
  int* cursor  = ibase + 1024 + 1025;
  int* perm    = ibase + 1024 + 1025 + 1024;
  float* outp  = (float*)d_out;

  hipMemcpyAsync(CGd, qhc::g_hc.buf, 20557 * sizeof(float), hipMemcpyHostToDevice, stream);

  qh_geom<<<NE / 256, 256, 0, stream>>>(pos, ei, LBNd, rbf, sh);
  qh_tk<<<NE / 32, 256, 0, stream>>>(sh, CGd, Tk);
  qh_nsc<<<NN, 128, 0, stream>>>(z, tptr, sptr, embed, tT, tH, sW1, sb1, sW2, sb2, nsc, x, x0);
  qh_zero<<<NN / 256, 256, 0, stream>>>(counts);
  qh_count<<<NE / 256, 256, 0, stream>>>(ei, counts);
  qh_scan<<<1, 1024, 0, stream>>>(counts, starts, cursor);
  qh_scatter<<<NE / 256, 256, 0, stream>>>(ei, cursor, perm);

  for (int l = 0; l < NLAY; l++) {
    qh_rad<<<NE / 16, 256, 0, stream>>>(rbf,
        rW1 + (size_t)l * 32 * 64, rb1 + (size_t)l * 64,
        rW2 + (size_t)l * 64 * 64, rb2 + (size_t)l * 64,
        rW3 + (size_t)l * 64 * 128, rb3 + (size_t)l * 128, wrad);
    qh_qk<<<NN, 256, 0, stream>>>(x0, Wq + (size_t)l * 16384, Wk + (size_t)l * 16384, qarr, karr);
    qh_logit<<<NE / 2, 256, 0, stream>>>(qarr, karr, ei, logits);
    qh_soft<<<NN, 64, 0, stream>>>(logits, starts, perm, alphaA);
    qh_msgatt<<<NN * 2, 256, 0, stream>>>(x, Tk, wrad, alphaA, starts, perm, ei, agg, att);
    qh_mixgemm<<<800, 256, 0, stream>>>(mixW + (size_t)l * 81920, agg);
    qh_gate<<<NN, 256, 0, stream>>>(agg, att, x, x0);
  }

  qh_prep<<<NN, 256, 0, stream>>>(x, nsc, Wii, Wij, pii, pij, EXPd, fm, awb, outp);
  qh_fij2<<<NE, 256, 0, stream>>>(ei, fm, awb, EXPd, outp);
}